// Round 1
// baseline (781.540 us; speedup 1.0000x reference)
//
#include <hip/hip_runtime.h>
#include <hip/hip_bf16.h>
#include <math.h>

#define PP 4096      // H*W
#define CCH 384      // channels
#define NB 16        // batch

__device__ __forceinline__ float sigmoidf_(float v){ return 1.f/(1.f+expf(-v)); }

// ---------------- prep: A matrices, Wsum, Wn, t1/t2 ----------------
__global__ __launch_bounds__(256) void k_prep(
    const float* __restrict__ rAl, const float* __restrict__ rU, const float* __restrict__ rV,
    const float* __restrict__ cAl, const float* __restrict__ cU, const float* __restrict__ cV,
    const float* __restrict__ rWs, const float* __restrict__ cWs,
    const float* __restrict__ g1w, const float* __restrict__ nw, const float* __restrict__ nb,
    float* __restrict__ Arow, float* __restrict__ Acol, float* __restrict__ Wsum,
    float* __restrict__ Wn, float* __restrict__ t1, float* __restrict__ t2)
{
  int bid = blockIdx.x, tid = threadIdx.x;
  if (bid < 576) {                       // Wsum: 384*384 = 147456
    int idx = bid*256 + tid;
    Wsum[idx] = rWs[idx] + cWs[idx];
  } else if (bid < 672) {                // Wn: 64*384 = 24576
    int idx = (bid-576)*256 + tid;
    Wn[idx] = g1w[idx]*nw[idx % CCH];
  } else {
    { // A matrices: A[i][j] = (i==j)*sigmoid(a[i]) + sum_r V[i,r]*U[j,r]
      int i = tid >> 4, j = tid & 15;
      float sr = 0.f, sc = 0.f;
      #pragma unroll
      for (int r=0;r<8;++r){ sr += rV[i*8+r]*rU[j*8+r]; sc += cV[i*8+r]*cU[j*8+r]; }
      if (i==j){ sr += sigmoidf_(rAl[i]); sc += sigmoidf_(cAl[i]); }
      Arow[tid] = sr; Acol[tid] = sc;
    }
    if (tid < 64) {
      float s1=0.f, s2=0.f;
      for (int c=0;c<CCH;++c){ s1 += g1w[tid*CCH+c]*nw[c]; s2 += nb[c]*g1w[tid*CCH+c]; }
      t1[tid]=s1; t2[tid]=s2;
    }
  }
}

// ---------------- skip GEMM: out[b,o,p] = sum_c Wsum[o,c] x[b,c,p] ----------------
// grid: 16 b * 6 otile * 64 ptile; block 256; 64x64 tile, 4x4 micro
__global__ __launch_bounds__(256) void k_gemm_skip(
    const float* __restrict__ x, const float* __restrict__ Wsum, float* __restrict__ outp)
{
  int bid = blockIdx.x;
  int pt = bid & 63; int ot = (bid >> 6) % 6; int b = bid / 384;
  int tid = threadIdx.x;
  int tp = tid & 15, to = tid >> 4;
  __shared__ __align__(16) float xs[16][64];
  __shared__ __align__(16) float wsT[16][68];
  float acc[4][4] = {};
  const float* xb = x + (size_t)b*CCH*PP + pt*64;
  int o0 = ot*64;
  int sp = tid & 63, scr = tid >> 6;
  int wo = tid >> 2, wq = (tid & 3)*4;
  const float* wrow = Wsum + (size_t)(o0 + wo)*CCH + wq;
  for (int c0=0; c0<CCH; c0+=16) {
    __syncthreads();
    #pragma unroll
    for (int r=0;r<4;++r)
      xs[scr + r*4][sp] = xb[(size_t)(c0 + scr + r*4)*PP + sp];
    float4 wv = *(const float4*)(wrow + c0);
    wsT[wq+0][wo]=wv.x; wsT[wq+1][wo]=wv.y; wsT[wq+2][wo]=wv.z; wsT[wq+3][wo]=wv.w;
    __syncthreads();
    #pragma unroll
    for (int cc=0;cc<16;++cc){
      float4 xv = *(const float4*)&xs[cc][tp*4];
      float4 wv2 = *(const float4*)&wsT[cc][to*4];
      float xa[4]={xv.x,xv.y,xv.z,xv.w};
      float wa[4]={wv2.x,wv2.y,wv2.z,wv2.w};
      #pragma unroll
      for (int i=0;i<4;++i)
        #pragma unroll
        for (int j=0;j<4;++j) acc[i][j] += wa[i]*xa[j];
    }
  }
  #pragma unroll
  for (int i=0;i<4;++i){
    float4 v = make_float4(acc[i][0],acc[i][1],acc[i][2],acc[i][3]);
    *(float4*)&outp[((size_t)(b*CCH + o0 + to*4 + i))*PP + pt*64 + tp*4] = v;
  }
}

// ---------------- ug GEMM: 64 outputs = [uR(16) gR(16) uC(16) gC(16)] ----------------
// epilogue: ugr[p,s] = (uR+binR)*sigmoid(gR+bgR), ugc likewise; layout (B,P,16)
__global__ __launch_bounds__(256) void k_gemm_ug(
    const float* __restrict__ x,
    const float* __restrict__ WinR, const float* __restrict__ WgR,
    const float* __restrict__ WinC, const float* __restrict__ WgC,
    const float* __restrict__ binR, const float* __restrict__ bgR,
    const float* __restrict__ binC, const float* __restrict__ bgC,
    float* __restrict__ ugr, float* __restrict__ ugc)
{
  int bid = blockIdx.x; int pt = bid & 63, b = bid >> 6;
  int tid = threadIdx.x, tp = tid & 15, to = tid >> 4;
  __shared__ __align__(16) float xs[16][64];
  __shared__ __align__(16) float wsT[16][68];
  __shared__ float tile[64*65];
  float acc[4][4] = {};
  const float* xb = x + (size_t)b*CCH*PP + pt*64;
  int sp = tid & 63, scr = tid >> 6;
  int wo = tid >> 2, wq = (tid & 3)*4;
  const float* wsrc = (wo<16)? WinR + (size_t)wo*CCH
                    : (wo<32)? WgR  + (size_t)(wo-16)*CCH
                    : (wo<48)? WinC + (size_t)(wo-32)*CCH
                             : WgC  + (size_t)(wo-48)*CCH;
  for (int c0=0; c0<CCH; c0+=16) {
    __syncthreads();
    #pragma unroll
    for (int r=0;r<4;++r)
      xs[scr + r*4][sp] = xb[(size_t)(c0 + scr + r*4)*PP + sp];
    float4 wv = *(const float4*)(wsrc + c0 + wq);
    wsT[wq+0][wo]=wv.x; wsT[wq+1][wo]=wv.y; wsT[wq+2][wo]=wv.z; wsT[wq+3][wo]=wv.w;
    __syncthreads();
    #pragma unroll
    for (int cc=0;cc<16;++cc){
      float4 xv = *(const float4*)&xs[cc][tp*4];
      float4 wv2 = *(const float4*)&wsT[cc][to*4];
      float xa[4]={xv.x,xv.y,xv.z,xv.w};
      float wa[4]={wv2.x,wv2.y,wv2.z,wv2.w};
      #pragma unroll
      for (int i=0;i<4;++i)
        #pragma unroll
        for (int j=0;j<4;++j) acc[i][j] += wa[i]*xa[j];
    }
  }
  #pragma unroll
  for (int i=0;i<4;++i)
    #pragma unroll
    for (int j=0;j<4;++j)
      tile[(to*4+i)*65 + tp*4+j] = acc[i][j];
  __syncthreads();
  for (int q = tid; q < 2048; q += 256) {
    int half = q >> 10, r = q & 1023, p = r >> 4, s = r & 15;
    const float* bu = half? binC : binR;
    const float* bg = half? bgC  : bgR;
    float u = tile[(half*32 + s)*65 + p] + bu[s];
    float g = sigmoidf_(tile[(half*32 + 16 + s)*65 + p] + bg[s]);
    float* dst = half? ugc : ugr;
    dst[((size_t)b*PP + pt*64 + p)*16 + s] = u*g;
  }
}

// ---------------- h1 GEMM: layernorm folded, gelu epilogue; h1 (B,64,P) ----------------
__global__ __launch_bounds__(256) void k_gemm_h1(
    const float* __restrict__ x, const float* __restrict__ Wn,
    const float* __restrict__ t1, const float* __restrict__ t2,
    const float* __restrict__ g1b, float* __restrict__ h1)
{
  int bid = blockIdx.x; int pt = bid & 63, b = bid >> 6;
  int tid = threadIdx.x, tp = tid & 15, to = tid >> 4;
  __shared__ __align__(16) float xs[16][64];
  __shared__ __align__(16) float wsT[16][68];
  float acc[4][4] = {};
  float sx[4] = {}, sx2[4] = {};
  const float* xb = x + (size_t)b*CCH*PP + pt*64;
  int sp = tid & 63, scr = tid >> 6;
  int wo = tid >> 2, wq = (tid & 3)*4;
  const float* wrow = Wn + (size_t)wo*CCH + wq;
  for (int c0=0; c0<CCH; c0+=16) {
    __syncthreads();
    #pragma unroll
    for (int r=0;r<4;++r)
      xs[scr + r*4][sp] = xb[(size_t)(c0 + scr + r*4)*PP + sp];
    float4 wv = *(const float4*)(wrow + c0);
    wsT[wq+0][wo]=wv.x; wsT[wq+1][wo]=wv.y; wsT[wq+2][wo]=wv.z; wsT[wq+3][wo]=wv.w;
    __syncthreads();
    #pragma unroll
    for (int cc=0;cc<16;++cc){
      float4 xv = *(const float4*)&xs[cc][tp*4];
      float4 wv2 = *(const float4*)&wsT[cc][to*4];
      float xa[4]={xv.x,xv.y,xv.z,xv.w};
      float wa[4]={wv2.x,wv2.y,wv2.z,wv2.w};
      #pragma unroll
      for (int j=0;j<4;++j){ sx[j] += xa[j]; sx2[j] += xa[j]*xa[j]; }
      #pragma unroll
      for (int i=0;i<4;++i)
        #pragma unroll
        for (int j=0;j<4;++j) acc[i][j] += wa[i]*xa[j];
    }
  }
  float mu[4], inv[4];
  #pragma unroll
  for (int j=0;j<4;++j){
    mu[j] = sx[j]*(1.f/CCH);
    float var = sx2[j]*(1.f/CCH) - mu[j]*mu[j];
    inv[j] = 1.f/sqrtf(var + 1e-6f);
  }
  #pragma unroll
  for (int i=0;i<4;++i){
    int o = to*4 + i;
    float t1o = t1[o], t2o = t2[o], gbo = g1b[o];
    float v[4];
    #pragma unroll
    for (int j=0;j<4;++j){
      float pre = inv[j]*(acc[i][j] - mu[j]*t1o) + t2o + gbo;
      v[j] = 0.5f*pre*(1.f + erff(pre*0.70710678118654752f));
    }
    *(float4*)&h1[((size_t)(b*64 + o))*PP + pt*64 + tp*4] = make_float4(v[0],v[1],v[2],v[3]);
  }
}

// ---------------- scan: fwd + aligned-reverse, hsum = hf[l]+hb[l]; (B,P,16) ----------------
// 2048 sequences (1024 row + 1024 col), 16 lanes each (one per state)
__global__ __launch_bounds__(256) void k_scan(
    const float* __restrict__ ugr, const float* __restrict__ ugc,
    const float* __restrict__ Arow, const float* __restrict__ Acol,
    float* __restrict__ hsR, float* __restrict__ hsC)
{
  int g = blockIdx.x*16 + (threadIdx.x >> 4);
  int lane = threadIdx.x & 63;
  int s = lane & 15;
  int base = lane & 48;
  bool isCol = g >= 1024;
  int gg = isCol ? g - 1024 : g;
  int b = gg >> 6, rc = gg & 63;
  const float* ug = isCol ? ugc : ugr;
  const float* A  = isCol ? Acol : Arow;
  float* outp     = isCol ? hsC : hsR;
  int p0 = b*PP + (isCol ? rc : rc*64);
  int stride = isCol ? 64 : 1;
  float ac[16];
  #pragma unroll
  for (int i=0;i<16;++i) ac[i] = A[i*16 + s];
  float h[64];
  float hf = 0.f;
  #pragma unroll
  for (int l=0;l<64;++l){
    float gu = ug[((size_t)(p0 + l*stride))*16 + s];
    float t = 0.f;
    #pragma unroll
    for (int i=0;i<16;++i) t += __shfl(hf, base + i, 64) * ac[i];
    hf = t + gu;
    h[l] = hf;
  }
  float hb = 0.f;
  #pragma unroll
  for (int l=63;l>=0;--l){
    float gu = ug[((size_t)(p0 + l*stride))*16 + s];
    float t = 0.f;
    #pragma unroll
    for (int i=0;i<16;++i) t += __shfl(hb, base + i, 64) * ac[i];
    hb = t + gu;
    outp[((size_t)(p0 + l*stride))*16 + s] = h[l] + hb;
  }
}

// ---------------- final: gate GEMM (C<-64) + Wout contraction + combine ----------------
// skip aliases outp (d_out): read-before-write per element, disjoint per block.
__global__ __launch_bounds__(256) void k_final(
    const float* __restrict__ x, const float* __restrict__ skip,
    const float* __restrict__ h1,
    const float* __restrict__ hsR, const float* __restrict__ hsC,
    const float* __restrict__ WoR, const float* __restrict__ WoC,
    const float* __restrict__ g2w, const float* __restrict__ g2b,
    const float* __restrict__ boR, const float* __restrict__ bsR,
    const float* __restrict__ boC, const float* __restrict__ bsC,
    float* __restrict__ outp)
{
  int bid = blockIdx.x; int pt = bid & 63, b = bid >> 6;
  int tid = threadIdx.x, tp = tid & 15, to = tid >> 4;
  __shared__ __align__(16) float h1t[64][64];
  __shared__ __align__(16) float g2t[64][68];
  __shared__ float hsRt[64][17], hsCt[64][17];
  __shared__ float woRt[64][17], woCt[64][17];
  const float* h1b = h1 + (size_t)b*64*PP + pt*64;
  #pragma unroll
  for (int r=0;r<16;++r){
    int idx = r*256 + tid; int o = idx >> 6, p = idx & 63;
    h1t[o][p] = h1b[(size_t)o*PP + p];
  }
  const float* hsRb = hsR + ((size_t)b*PP + pt*64)*16;
  const float* hsCb = hsC + ((size_t)b*PP + pt*64)*16;
  #pragma unroll
  for (int r=0;r<4;++r){
    int idx = r*256 + tid; int p = idx >> 4, s = idx & 15;
    hsRt[p][s] = hsRb[idx]; hsCt[p][s] = hsCb[idx];
  }
  for (int ct=0; ct<6; ++ct){
    int c0 = ct*64;
    __syncthreads();
    #pragma unroll
    for (int r=0;r<16;++r){
      int idx = r*256 + tid; int o = idx & 63, cl = idx >> 6;
      g2t[o][cl] = g2w[(size_t)(c0+cl)*64 + o];
    }
    #pragma unroll
    for (int r=0;r<4;++r){
      int idx = r*256 + tid; int cl = idx >> 4, s = idx & 15;
      woRt[cl][s] = WoR[(size_t)(c0+cl)*16 + s];
      woCt[cl][s] = WoC[(size_t)(c0+cl)*16 + s];
    }
    __syncthreads();
    float gac[4][4] = {}, yac[4][4] = {};
    #pragma unroll
    for (int o=0;o<64;++o){
      float4 hv = *(const float4*)&h1t[o][tp*4];
      float4 gv = *(const float4*)&g2t[o][to*4];
      float ha[4]={hv.x,hv.y,hv.z,hv.w}, ga[4]={gv.x,gv.y,gv.z,gv.w};
      #pragma unroll
      for (int i=0;i<4;++i)
        #pragma unroll
        for (int j=0;j<4;++j) gac[i][j] += ga[i]*ha[j];
    }
    #pragma unroll
    for (int s=0;s<16;++s){
      float hr[4], hc[4];
      #pragma unroll
      for (int j=0;j<4;++j){ hr[j]=hsRt[tp*4+j][s]; hc[j]=hsCt[tp*4+j][s]; }
      #pragma unroll
      for (int i=0;i<4;++i){
        float wr = woRt[to*4+i][s], wc = woCt[to*4+i][s];
        #pragma unroll
        for (int j=0;j<4;++j) yac[i][j] += wr*hr[j] + wc*hc[j];
      }
    }
    #pragma unroll
    for (int i=0;i<4;++i){
      int c = c0 + to*4 + i;
      float cb = 2.f*(boR[c]+bsR[c]+boC[c]+bsC[c]);
      float gb = g2b[c];
      size_t baseA = ((size_t)(b*CCH + c))*PP + pt*64 + tp*4;
      float4 sk = *(const float4*)&skip[baseA];
      float4 xv = *(const float4*)&x[baseA];
      float ska[4]={sk.x,sk.y,sk.z,sk.w}, xa[4]={xv.x,xv.y,xv.z,xv.w};
      float o4[4];
      #pragma unroll
      for (int j=0;j<4;++j){
        float y = 0.25f*(yac[i][j] + 2.f*ska[j] + cb);
        float gt = sigmoidf_(gac[i][j] + gb);
        o4[j] = gt*y + (1.f-gt)*xa[j];
      }
      *(float4*)&outp[baseA] = make_float4(o4[0],o4[1],o4[2],o4[3]);
    }
  }
}

extern "C" void kernel_launch(void* const* d_in, const int* in_sizes, int n_in,
                              void* d_out, int out_size, void* d_ws, size_t ws_size,
                              hipStream_t stream)
{
  const float* x    = (const float*)d_in[0];
  const float* rAl  = (const float*)d_in[1];
  const float* rU   = (const float*)d_in[2];
  const float* rV   = (const float*)d_in[3];
  const float* rWin = (const float*)d_in[4];
  const float* rbin = (const float*)d_in[5];
  const float* rWg  = (const float*)d_in[6];
  const float* rbg  = (const float*)d_in[7];
  const float* rWo  = (const float*)d_in[8];
  const float* rbo  = (const float*)d_in[9];
  const float* rWs  = (const float*)d_in[10];
  const float* rbs  = (const float*)d_in[11];
  const float* cAl  = (const float*)d_in[12];
  const float* cU   = (const float*)d_in[13];
  const float* cV   = (const float*)d_in[14];
  const float* cWin = (const float*)d_in[15];
  const float* cbin = (const float*)d_in[16];
  const float* cWg  = (const float*)d_in[17];
  const float* cbg  = (const float*)d_in[18];
  const float* cWo  = (const float*)d_in[19];
  const float* cbo  = (const float*)d_in[20];
  const float* cWs  = (const float*)d_in[21];
  const float* cbs  = (const float*)d_in[22];
  const float* g1w  = (const float*)d_in[23];
  const float* g1b  = (const float*)d_in[24];
  const float* g2w  = (const float*)d_in[25];
  const float* g2b  = (const float*)d_in[26];
  const float* nw   = (const float*)d_in[27];
  const float* nb   = (const float*)d_in[28];

  float* ws  = (float*)d_ws;
  float* ugr = ws;                    // 1048576  (B,P,16)
  float* ugc = ugr + 1048576;         // 1048576
  float* h1  = ugc + 1048576;         // 4194304  (B,64,P)
  float* hsR = h1  + 4194304;         // 1048576  (B,P,16)
  float* hsC = hsR + 1048576;         // 1048576
  float* Arow= hsC + 1048576;         // 256
  float* Acol= Arow + 256;            // 256
  float* Wsum= Acol + 256;            // 147456
  float* Wn  = Wsum + 147456;         // 24576
  float* t1  = Wn   + 24576;          // 64
  float* t2  = t1   + 64;             // 64
  float* outp = (float*)d_out;

  k_prep<<<673, 256, 0, stream>>>(rAl,rU,rV,cAl,cU,cV,rWs,cWs,g1w,nw,nb,
                                  Arow,Acol,Wsum,Wn,t1,t2);
  k_gemm_ug<<<1024, 256, 0, stream>>>(x,rWin,rWg,cWin,cWg,rbin,rbg,cbin,cbg,ugr,ugc);
  k_gemm_h1<<<1024, 256, 0, stream>>>(x,Wn,t1,t2,g1b,h1);
  k_gemm_skip<<<6144, 256, 0, stream>>>(x,Wsum,outp);
  k_scan<<<128, 256, 0, stream>>>(ugr,ugc,Arow,Acol,hsR,hsC);
  k_final<<<1024, 256, 0, stream>>>(x,outp,h1,hsR,hsC,rWo,cWo,g2w,g2b,
                                    rbo,rbs,cbo,cbs,outp);
}

// Round 2
// 548.733 us; speedup vs baseline: 1.4243x; 1.4243x over previous
//
#include <hip/hip_runtime.h>
#include <hip/hip_bf16.h>
#include <math.h>

#define PP 4096      // H*W
#define CCH 384      // channels
#define NB 16        // batch

__device__ __forceinline__ float sigmoidf_(float v){ return 1.f/(1.f+expf(-v)); }

// ---------------- prep: A matrices, Wsum, Wn, t1/t2 ----------------
__global__ __launch_bounds__(256) void k_prep(
    const float* __restrict__ rAl, const float* __restrict__ rU, const float* __restrict__ rV,
    const float* __restrict__ cAl, const float* __restrict__ cU, const float* __restrict__ cV,
    const float* __restrict__ rWs, const float* __restrict__ cWs,
    const float* __restrict__ g1w, const float* __restrict__ nw, const float* __restrict__ nb,
    float* __restrict__ Arow, float* __restrict__ Acol, float* __restrict__ Wsum,
    float* __restrict__ Wn, float* __restrict__ t1, float* __restrict__ t2)
{
  int bid = blockIdx.x, tid = threadIdx.x;
  if (bid < 576) {                       // Wsum: 384*384 = 147456
    int idx = bid*256 + tid;
    Wsum[idx] = rWs[idx] + cWs[idx];
  } else if (bid < 672) {                // Wn: 64*384 = 24576
    int idx = (bid-576)*256 + tid;
    Wn[idx] = g1w[idx]*nw[idx % CCH];
  } else {
    { // A matrices: A[i][j] = (i==j)*sigmoid(a[i]) + sum_r V[i,r]*U[j,r]
      int i = tid >> 4, j = tid & 15;
      float sr = 0.f, sc = 0.f;
      #pragma unroll
      for (int r=0;r<8;++r){ sr += rV[i*8+r]*rU[j*8+r]; sc += cV[i*8+r]*cU[j*8+r]; }
      if (i==j){ sr += sigmoidf_(rAl[i]); sc += sigmoidf_(cAl[i]); }
      Arow[tid] = sr; Acol[tid] = sc;
    }
    if (tid < 64) {
      float s1=0.f, s2=0.f;
      for (int c=0;c<CCH;++c){ s1 += g1w[tid*CCH+c]*nw[c]; s2 += nb[c]*g1w[tid*CCH+c]; }
      t1[tid]=s1; t2[tid]=s2;
    }
  }
}

// ---------------- ug GEMM: 64 outputs = [uR(16) gR(16) uC(16) gC(16)] ----------------
__global__ __launch_bounds__(256) void k_gemm_ug(
    const float* __restrict__ x,
    const float* __restrict__ WinR, const float* __restrict__ WgR,
    const float* __restrict__ WinC, const float* __restrict__ WgC,
    const float* __restrict__ binR, const float* __restrict__ bgR,
    const float* __restrict__ binC, const float* __restrict__ bgC,
    float* __restrict__ ugr, float* __restrict__ ugc)
{
  int bid = blockIdx.x; int pt = bid & 63, b = bid >> 6;
  int tid = threadIdx.x, tp = tid & 15, to = tid >> 4;
  __shared__ __align__(16) float xs[16][64];
  __shared__ __align__(16) float wsT[16][68];
  __shared__ float tile[64*65];
  float acc[4][4] = {};
  const float* xb = x + (size_t)b*CCH*PP + pt*64;
  int sp = tid & 63, scr = tid >> 6;
  int wo = tid >> 2, wq = (tid & 3)*4;
  const float* wsrc = (wo<16)? WinR + (size_t)wo*CCH
                    : (wo<32)? WgR  + (size_t)(wo-16)*CCH
                    : (wo<48)? WinC + (size_t)(wo-32)*CCH
                             : WgC  + (size_t)(wo-48)*CCH;
  for (int c0=0; c0<CCH; c0+=16) {
    __syncthreads();
    #pragma unroll
    for (int r=0;r<4;++r)
      xs[scr + r*4][sp] = xb[(size_t)(c0 + scr + r*4)*PP + sp];
    float4 wv = *(const float4*)(wsrc + c0 + wq);
    wsT[wq+0][wo]=wv.x; wsT[wq+1][wo]=wv.y; wsT[wq+2][wo]=wv.z; wsT[wq+3][wo]=wv.w;
    __syncthreads();
    #pragma unroll
    for (int cc=0;cc<16;++cc){
      float4 xv = *(const float4*)&xs[cc][tp*4];
      float4 wv2 = *(const float4*)&wsT[cc][to*4];
      float xa[4]={xv.x,xv.y,xv.z,xv.w};
      float wa[4]={wv2.x,wv2.y,wv2.z,wv2.w};
      #pragma unroll
      for (int i=0;i<4;++i)
        #pragma unroll
        for (int j=0;j<4;++j) acc[i][j] += wa[i]*xa[j];
    }
  }
  #pragma unroll
  for (int i=0;i<4;++i)
    #pragma unroll
    for (int j=0;j<4;++j)
      tile[(to*4+i)*65 + tp*4+j] = acc[i][j];
  __syncthreads();
  for (int q = tid; q < 2048; q += 256) {
    int half = q >> 10, r = q & 1023, p = r >> 4, s = r & 15;
    const float* bu = half? binC : binR;
    const float* bg = half? bgC  : bgR;
    float u = tile[(half*32 + s)*65 + p] + bu[s];
    float g = sigmoidf_(tile[(half*32 + 16 + s)*65 + p] + bg[s]);
    float* dst = half? ugc : ugr;
    dst[((size_t)b*PP + pt*64 + p)*16 + s] = u*g;
  }
}

// ---------------- h1 GEMM: layernorm folded, gelu epilogue; h1 (B,64,P) ----------------
__global__ __launch_bounds__(256) void k_gemm_h1(
    const float* __restrict__ x, const float* __restrict__ Wn,
    const float* __restrict__ t1, const float* __restrict__ t2,
    const float* __restrict__ g1b, float* __restrict__ h1)
{
  int bid = blockIdx.x; int pt = bid & 63, b = bid >> 6;
  int tid = threadIdx.x, tp = tid & 15, to = tid >> 4;
  __shared__ __align__(16) float xs[16][64];
  __shared__ __align__(16) float wsT[16][68];
  float acc[4][4] = {};
  float sx[4] = {}, sx2[4] = {};
  const float* xb = x + (size_t)b*CCH*PP + pt*64;
  int sp = tid & 63, scr = tid >> 6;
  int wo = tid >> 2, wq = (tid & 3)*4;
  const float* wrow = Wn + (size_t)wo*CCH + wq;
  for (int c0=0; c0<CCH; c0+=16) {
    __syncthreads();
    #pragma unroll
    for (int r=0;r<4;++r)
      xs[scr + r*4][sp] = xb[(size_t)(c0 + scr + r*4)*PP + sp];
    float4 wv = *(const float4*)(wrow + c0);
    wsT[wq+0][wo]=wv.x; wsT[wq+1][wo]=wv.y; wsT[wq+2][wo]=wv.z; wsT[wq+3][wo]=wv.w;
    __syncthreads();
    #pragma unroll
    for (int cc=0;cc<16;++cc){
      float4 xv = *(const float4*)&xs[cc][tp*4];
      float4 wv2 = *(const float4*)&wsT[cc][to*4];
      float xa[4]={xv.x,xv.y,xv.z,xv.w};
      float wa[4]={wv2.x,wv2.y,wv2.z,wv2.w};
      #pragma unroll
      for (int j=0;j<4;++j){ sx[j] += xa[j]; sx2[j] += xa[j]*xa[j]; }
      #pragma unroll
      for (int i=0;i<4;++i)
        #pragma unroll
        for (int j=0;j<4;++j) acc[i][j] += wa[i]*xa[j];
    }
  }
  float mu[4], inv[4];
  #pragma unroll
  for (int j=0;j<4;++j){
    mu[j] = sx[j]*(1.f/CCH);
    float var = sx2[j]*(1.f/CCH) - mu[j]*mu[j];
    inv[j] = 1.f/sqrtf(var + 1e-6f);
  }
  #pragma unroll
  for (int i=0;i<4;++i){
    int o = to*4 + i;
    float t1o = t1[o], t2o = t2[o], gbo = g1b[o];
    float v[4];
    #pragma unroll
    for (int j=0;j<4;++j){
      float pre = inv[j]*(acc[i][j] - mu[j]*t1o) + t2o + gbo;
      v[j] = 0.5f*pre*(1.f + erff(pre*0.70710678118654752f));
    }
    *(float4*)&h1[((size_t)(b*64 + o))*PP + pt*64 + tp*4] = make_float4(v[0],v[1],v[2],v[3]);
  }
}

// ---------------- scan: fwd + aligned-reverse, hsum = hf[l]+hb[l]; (B,P,16) ----------------
__global__ __launch_bounds__(256) void k_scan(
    const float* __restrict__ ugr, const float* __restrict__ ugc,
    const float* __restrict__ Arow, const float* __restrict__ Acol,
    float* __restrict__ hsR, float* __restrict__ hsC)
{
  int g = blockIdx.x*16 + (threadIdx.x >> 4);
  int lane = threadIdx.x & 63;
  int s = lane & 15;
  int base = lane & 48;
  bool isCol = g >= 1024;
  int gg = isCol ? g - 1024 : g;
  int b = gg >> 6, rc = gg & 63;
  const float* ug = isCol ? ugc : ugr;
  const float* A  = isCol ? Acol : Arow;
  float* outp     = isCol ? hsC : hsR;
  int p0 = b*PP + (isCol ? rc : rc*64);
  int stride = isCol ? 64 : 1;
  float ac[16];
  #pragma unroll
  for (int i=0;i<16;++i) ac[i] = A[i*16 + s];
  float h[64];
  float hf = 0.f;
  #pragma unroll
  for (int l=0;l<64;++l){
    float gu = ug[((size_t)(p0 + l*stride))*16 + s];
    float t = 0.f;
    #pragma unroll
    for (int i=0;i<16;++i) t += __shfl(hf, base + i, 64) * ac[i];
    hf = t + gu;
    h[l] = hf;
  }
  float hb = 0.f;
  #pragma unroll
  for (int l=63;l>=0;--l){
    float gu = ug[((size_t)(p0 + l*stride))*16 + s];
    float t = 0.f;
    #pragma unroll
    for (int i=0;i<16;++i) t += __shfl(hb, base + i, 64) * ac[i];
    hb = t + gu;
    outp[((size_t)(p0 + l*stride))*16 + s] = h[l] + hb;
  }
}

// ---------------- fused: skip GEMM (K=384) + gate GEMM (K=64) + Wout (K=2x16) + combine ----
// grid: 16 b * 6 ctile * 64 ptile; block 256; 64x64 out tile, 4x4 micro
__global__ __launch_bounds__(256) void k_fused(
    const float* __restrict__ x, const float* __restrict__ Wsum,
    const float* __restrict__ h1, const float* __restrict__ g2w,
    const float* __restrict__ hsR, const float* __restrict__ hsC,
    const float* __restrict__ WoR, const float* __restrict__ WoC,
    const float* __restrict__ g2b,
    const float* __restrict__ boR, const float* __restrict__ bsR,
    const float* __restrict__ boC, const float* __restrict__ bsC,
    float* __restrict__ outp)
{
  int bid = blockIdx.x;
  int pt = bid & 63; int ct = (bid >> 6) % 6; int b = bid / 384;
  int tid = threadIdx.x;
  int tp = tid & 15, to = tid >> 4;
  __shared__ __align__(16) float xs[16][64];
  __shared__ __align__(16) float wsT[16][68];
  __shared__ float hsRt[64][17], hsCt[64][17];
  __shared__ float woRt[64][17], woCt[64][17];
  float accS[4][4] = {};   // skip = Wsum . x
  float gac[4][4] = {};    // gate pre-act = g2w . h1
  float yac[4][4] = {};    // Wout contraction
  int c0 = ct*64;
  int sp = tid & 63, scr = tid >> 6;
  int wo = tid >> 2, wq = (tid & 3)*4;

  // ---- phase A: skip GEMM over x, K=384 ----
  {
    const float* xb   = x + (size_t)b*CCH*PP + pt*64;
    const float* wrow = Wsum + (size_t)(c0 + wo)*CCH + wq;
    for (int k0=0; k0<CCH; k0+=16) {
      __syncthreads();
      #pragma unroll
      for (int r=0;r<4;++r)
        xs[scr + r*4][sp] = xb[(size_t)(k0 + scr + r*4)*PP + sp];
      float4 wv = *(const float4*)(wrow + k0);
      wsT[wq+0][wo]=wv.x; wsT[wq+1][wo]=wv.y; wsT[wq+2][wo]=wv.z; wsT[wq+3][wo]=wv.w;
      __syncthreads();
      #pragma unroll
      for (int cc=0;cc<16;++cc){
        float4 xv = *(const float4*)&xs[cc][tp*4];
        float4 wv2 = *(const float4*)&wsT[cc][to*4];
        float xa[4]={xv.x,xv.y,xv.z,xv.w};
        float wa[4]={wv2.x,wv2.y,wv2.z,wv2.w};
        #pragma unroll
        for (int i=0;i<4;++i)
          #pragma unroll
          for (int j=0;j<4;++j) accS[i][j] += wa[i]*xa[j];
      }
    }
  }
  // ---- phase B: gate GEMM over h1, K=64 (same layout: row stride PP) ----
  {
    const float* hb   = h1 + (size_t)b*64*PP + pt*64;
    const float* grow = g2w + (size_t)(c0 + wo)*64 + wq;
    for (int k0=0; k0<64; k0+=16) {
      __syncthreads();
      #pragma unroll
      for (int r=0;r<4;++r)
        xs[scr + r*4][sp] = hb[(size_t)(k0 + scr + r*4)*PP + sp];
      float4 wv = *(const float4*)(grow + k0);
      wsT[wq+0][wo]=wv.x; wsT[wq+1][wo]=wv.y; wsT[wq+2][wo]=wv.z; wsT[wq+3][wo]=wv.w;
      __syncthreads();
      #pragma unroll
      for (int cc=0;cc<16;++cc){
        float4 xv = *(const float4*)&xs[cc][tp*4];
        float4 wv2 = *(const float4*)&wsT[cc][to*4];
        float xa[4]={xv.x,xv.y,xv.z,xv.w};
        float wa[4]={wv2.x,wv2.y,wv2.z,wv2.w};
        #pragma unroll
        for (int i=0;i<4;++i)
          #pragma unroll
          for (int j=0;j<4;++j) gac[i][j] += wa[i]*xa[j];
      }
    }
  }
  // ---- phase C: Wout contraction, K=16 (row) + 16 (col) ----
  {
    const float* hsRb = hsR + ((size_t)b*PP + pt*64)*16;
    const float* hsCb = hsC + ((size_t)b*PP + pt*64)*16;
    __syncthreads();   // phase B reads of xs/wsT complete (different arrays below, but keep ordering clean)
    #pragma unroll
    for (int r=0;r<4;++r){
      int idx = r*256 + tid; int p = idx >> 4, s = idx & 15;
      hsRt[p][s] = hsRb[idx]; hsCt[p][s] = hsCb[idx];
      woRt[p][s] = WoR[(size_t)(c0+p)*16 + s];
      woCt[p][s] = WoC[(size_t)(c0+p)*16 + s];
    }
    __syncthreads();
    #pragma unroll
    for (int s=0;s<16;++s){
      float hr[4], hc[4];
      #pragma unroll
      for (int j=0;j<4;++j){ hr[j]=hsRt[tp*4+j][s]; hc[j]=hsCt[tp*4+j][s]; }
      #pragma unroll
      for (int i=0;i<4;++i){
        float wr = woRt[to*4+i][s], wc = woCt[to*4+i][s];
        #pragma unroll
        for (int j=0;j<4;++j) yac[i][j] += wr*hr[j] + wc*hc[j];
      }
    }
  }
  // ---- epilogue: combine + write ----
  #pragma unroll
  for (int i=0;i<4;++i){
    int c = c0 + to*4 + i;
    float cb = 2.f*(boR[c]+bsR[c]+boC[c]+bsC[c]);
    float gb = g2b[c];
    size_t baseA = ((size_t)(b*CCH + c))*PP + pt*64 + tp*4;
    float4 xv = *(const float4*)&x[baseA];
    float xa[4]={xv.x,xv.y,xv.z,xv.w};
    float o4[4];
    #pragma unroll
    for (int j=0;j<4;++j){
      float y = 0.25f*(yac[i][j] + 2.f*accS[i][j] + cb);
      float gt = sigmoidf_(gac[i][j] + gb);
      o4[j] = gt*y + (1.f-gt)*xa[j];
    }
    *(float4*)&outp[baseA] = make_float4(o4[0],o4[1],o4[2],o4[3]);
  }
}

extern "C" void kernel_launch(void* const* d_in, const int* in_sizes, int n_in,
                              void* d_out, int out_size, void* d_ws, size_t ws_size,
                              hipStream_t stream)
{
  const float* x    = (const float*)d_in[0];
  const float* rAl  = (const float*)d_in[1];
  const float* rU   = (const float*)d_in[2];
  const float* rV   = (const float*)d_in[3];
  const float* rWin = (const float*)d_in[4];
  const float* rbin = (const float*)d_in[5];
  const float* rWg  = (const float*)d_in[6];
  const float* rbg  = (const float*)d_in[7];
  const float* rWo  = (const float*)d_in[8];
  const float* rbo  = (const float*)d_in[9];
  const float* rWs  = (const float*)d_in[10];
  const float* rbs  = (const float*)d_in[11];
  const float* cAl  = (const float*)d_in[12];
  const float* cU   = (const float*)d_in[13];
  const float* cV   = (const float*)d_in[14];
  const float* cWin = (const float*)d_in[15];
  const float* cbin = (const float*)d_in[16];
  const float* cWg  = (const float*)d_in[17];
  const float* cbg  = (const float*)d_in[18];
  const float* cWo  = (const float*)d_in[19];
  const float* cbo  = (const float*)d_in[20];
  const float* cWs  = (const float*)d_in[21];
  const float* cbs  = (const float*)d_in[22];
  const float* g1w  = (const float*)d_in[23];
  const float* g1b  = (const float*)d_in[24];
  const float* g2w  = (const float*)d_in[25];
  const float* g2b  = (const float*)d_in[26];
  const float* nw   = (const float*)d_in[27];
  const float* nb   = (const float*)d_in[28];

  float* ws  = (float*)d_ws;
  float* ugr = ws;                    // 1048576  (B,P,16)
  float* ugc = ugr + 1048576;         // 1048576
  float* h1  = ugc + 1048576;         // 4194304  (B,64,P)
  float* hsR = h1  + 4194304;         // 1048576  (B,P,16)
  float* hsC = hsR + 1048576;         // 1048576
  float* Arow= hsC + 1048576;         // 256
  float* Acol= Arow + 256;            // 256
  float* Wsum= Acol + 256;            // 147456
  float* Wn  = Wsum + 147456;         // 24576
  float* t1  = Wn   + 24576;          // 64
  float* t2  = t1   + 64;             // 64
  float* outp = (float*)d_out;

  k_prep<<<673, 256, 0, stream>>>(rAl,rU,rV,cAl,cU,cV,rWs,cWs,g1w,nw,nb,
                                  Arow,Acol,Wsum,Wn,t1,t2);
  k_gemm_ug<<<1024, 256, 0, stream>>>(x,rWin,rWg,cWin,cWg,rbin,rbg,cbin,cbg,ugr,ugc);
  k_gemm_h1<<<1024, 256, 0, stream>>>(x,Wn,t1,t2,g1b,h1);
  k_scan<<<128, 256, 0, stream>>>(ugr,ugc,Arow,Acol,hsR,hsC);
  k_fused<<<6144, 256, 0, stream>>>(x,Wsum,h1,g2w,hsR,hsC,rWo,cWo,g2b,
                                    rbo,rbs,cbo,cbs,outp);
}

// Round 3
// 350.496 us; speedup vs baseline: 2.2298x; 1.5656x over previous
//
#include <hip/hip_runtime.h>
#include <hip/hip_bf16.h>
#include <math.h>

#define PP 4096      // H*W
#define CCH 384      // channels
#define NB 16        // batch

using short8 = __attribute__((ext_vector_type(8))) short;
using f32x4  = __attribute__((ext_vector_type(4))) float;

__device__ __forceinline__ float sigmoidf_(float v){ return 1.f/(1.f+expf(-v)); }
__device__ __forceinline__ unsigned int f2bf(float f){
  __hip_bfloat16 h = __float2bfloat16(f);
  return (unsigned int)*reinterpret_cast<unsigned short*>(&h);
}

// ---------------- prep: A matrices, bf16 weights, t1/t2 ----------------
// grid 865: [0,576) WsumBf; [576,768) WcatBf; [768,864) g2wBf; 864: A + t1/t2
__global__ __launch_bounds__(256) void k_prep(
    const float* __restrict__ rAl, const float* __restrict__ rU, const float* __restrict__ rV,
    const float* __restrict__ cAl, const float* __restrict__ cU, const float* __restrict__ cV,
    const float* __restrict__ rWs, const float* __restrict__ cWs,
    const float* __restrict__ WinR, const float* __restrict__ WgR,
    const float* __restrict__ WinC, const float* __restrict__ WgC,
    const float* __restrict__ g1w, const float* __restrict__ nw, const float* __restrict__ nb,
    const float* __restrict__ g2w,
    float* __restrict__ Arow, float* __restrict__ Acol,
    unsigned short* __restrict__ WsumBf, unsigned short* __restrict__ WcatBf,
    unsigned short* __restrict__ g2wBf,
    float* __restrict__ t1, float* __restrict__ t2)
{
  int bid = blockIdx.x, tid = threadIdx.x;
  if (bid < 576) {                       // WsumBf: 384*384
    int idx = bid*256 + tid;
    WsumBf[idx] = (unsigned short)f2bf(rWs[idx] + cWs[idx]);
  } else if (bid < 768) {                // WcatBf: 128*384 = 49152
    int idx = (bid-576)*256 + tid;
    int row = idx / CCH, col = idx - row*CCH;
    float v;
    if      (row < 16)  v = WinR[row*CCH + col];
    else if (row < 32)  v = WgR [(row-16)*CCH + col];
    else if (row < 48)  v = WinC[(row-32)*CCH + col];
    else if (row < 64)  v = WgC [(row-48)*CCH + col];
    else                v = g1w[(row-64)*CCH + col]*nw[col];
    WcatBf[idx] = (unsigned short)f2bf(v);
  } else if (bid < 864) {                // g2wBf: 384*64 = 24576
    int idx = (bid-768)*256 + tid;
    g2wBf[idx] = (unsigned short)f2bf(g2w[idx]);
  } else {
    { // A[i][j] = (i==j)*sigmoid(a[i]) + sum_r V[i,r]*U[j,r]
      int i = tid >> 4, j = tid & 15;
      float sr = 0.f, sc = 0.f;
      #pragma unroll
      for (int r=0;r<8;++r){ sr += rV[i*8+r]*rU[j*8+r]; sc += cV[i*8+r]*cU[j*8+r]; }
      if (i==j){ sr += sigmoidf_(rAl[i]); sc += sigmoidf_(cAl[i]); }
      Arow[tid] = sr; Acol[tid] = sc;
    }
    if (tid < 64) {
      float s1=0.f, s2=0.f;
      for (int c=0;c<CCH;++c){ s1 += g1w[tid*CCH+c]*nw[c]; s2 += nb[c]*g1w[tid*CCH+c]; }
      t1[tid]=s1; t2[tid]=s2;
    }
  }
}

// ---------------- xpose: x (b,c,p) -> xbf (b,p,c) bf16; per-position mean/invstd ----
// grid 1024 = (b, pt); block 256
__global__ __launch_bounds__(256) void k_xpose(
    const float* __restrict__ x, unsigned short* __restrict__ xbf,
    float* __restrict__ meanA, float* __restrict__ invA)
{
  int b = blockIdx.x >> 6, pt = blockIdx.x & 63;
  int t = threadIdx.x;
  int pl = t & 63, g4 = t >> 6;
  __shared__ float tile[64][65];
  float sx = 0.f, sx2 = 0.f;
  const float* xb = x + (size_t)b*CCH*PP + pt*64;
  int pw = t >> 2, q = t & 3;
  unsigned short* xo = xbf + ((size_t)(b*PP + pt*64 + pw))*CCH;
  for (int cc = 0; cc < 6; ++cc) {
    __syncthreads();
    #pragma unroll
    for (int r=0;r<16;++r)
      tile[r*4+g4][pl] = xb[(size_t)(cc*64 + r*4 + g4)*PP + pl];
    __syncthreads();
    #pragma unroll
    for (int j=0;j<16;++j){ float v = tile[g4*16+j][pl]; sx += v; sx2 += v*v; }
    #pragma unroll
    for (int j=0;j<4;++j){
      unsigned int u0 = f2bf(tile[q*16+j*4+0][pw]);
      unsigned int u1 = f2bf(tile[q*16+j*4+1][pw]);
      unsigned int u2 = f2bf(tile[q*16+j*4+2][pw]);
      unsigned int u3 = f2bf(tile[q*16+j*4+3][pw]);
      uint2 o; o.x = u0 | (u1<<16); o.y = u2 | (u3<<16);
      *reinterpret_cast<uint2*>(xo + cc*64 + q*16 + j*4) = o;
    }
  }
  __syncthreads();
  float* red = &tile[0][0];
  red[g4*64 + pl] = sx;
  red[256 + g4*64 + pl] = sx2;
  __syncthreads();
  if (t < 64) {
    float s1 = red[t] + red[64+t] + red[128+t] + red[192+t];
    float s2 = red[256+t] + red[320+t] + red[384+t] + red[448+t];
    float mu = s1 * (1.f/CCH);
    float var = s2 * (1.f/CCH) - mu*mu;
    meanA[b*PP + pt*64 + t] = mu;
    invA [b*PP + pt*64 + t] = rsqrtf(var + 1e-6f);
  }
}

// ---------------- front: MFMA GEMM, 128 outs = [uR gR uC gC h1pre(64)] x K=384 ----
// grid 1024 = (b, pt); 4 waves, wave w owns rows w*32..w*32+31 (2 m-frags) x 64 p
__global__ __launch_bounds__(256) void k_front(
    const unsigned short* __restrict__ xbf, const unsigned short* __restrict__ WcatBf,
    const float* __restrict__ binR, const float* __restrict__ bgR,
    const float* __restrict__ binC, const float* __restrict__ bgC,
    const float* __restrict__ meanA, const float* __restrict__ invA,
    const float* __restrict__ t1, const float* __restrict__ t2,
    const float* __restrict__ g1b,
    float* __restrict__ ugr, float* __restrict__ ugc,
    unsigned short* __restrict__ h1bf)
{
  int b = blockIdx.x >> 6, pt = blockIdx.x & 63;
  int t = threadIdx.x;
  int w = t >> 6, l = t & 63;
  int lr = l & 15, kb8 = (l >> 4) * 8;
  f32x4 acc[2][4] = {};
  const unsigned short* wbase0 = WcatBf + (size_t)(w*32 + lr)*CCH + kb8;
  const unsigned short* wbase1 = wbase0 + 16*CCH;
  const unsigned short* xbase  = xbf + ((size_t)(b*PP + pt*64 + lr))*CCH + kb8;
  #pragma unroll
  for (int ks = 0; ks < 12; ++ks) {
    int k0 = ks*32;
    short8 a0 = *(const short8*)(wbase0 + k0);
    short8 a1 = *(const short8*)(wbase1 + k0);
    short8 bv[4];
    #pragma unroll
    for (int nf=0; nf<4; ++nf)
      bv[nf] = *(const short8*)(xbase + (size_t)nf*16*CCH + k0);
    #pragma unroll
    for (int nf=0; nf<4; ++nf){
      acc[0][nf] = __builtin_amdgcn_mfma_f32_16x16x32_bf16(a0, bv[nf], acc[0][nf], 0,0,0);
      acc[1][nf] = __builtin_amdgcn_mfma_f32_16x16x32_bf16(a1, bv[nf], acc[1][nf], 0,0,0);
    }
  }
  if (w < 2) {
    // ug epilogue: mi=0 -> u (s=(l>>4)*4+r), mi=1 -> g
    const float* bu = w ? binC : binR;
    const float* bg = w ? bgC  : bgR;
    float* dst = w ? ugc : ugr;
    float bus[4], bgs[4];
    #pragma unroll
    for (int r=0;r<4;++r){ int s = (l>>4)*4 + r; bus[r]=bu[s]; bgs[r]=bg[s]; }
    #pragma unroll
    for (int nf=0; nf<4; ++nf){
      size_t pbase = ((size_t)(b*PP + pt*64 + nf*16 + lr))*16;
      #pragma unroll
      for (int r=0;r<4;++r){
        int s = (l>>4)*4 + r;
        float u = acc[0][nf][r] + bus[r];
        float g = sigmoidf_(acc[1][nf][r] + bgs[r]);
        dst[pbase + s] = u*g;
      }
    }
  } else {
    // h1 epilogue: o = (w-2)*32 + mi*16 + (l>>4)*4 + r
    int ob = (w-2)*32 + ((l>>4)*4);
    float t1o[2][4], t2o[2][4], gbo[2][4];
    #pragma unroll
    for (int mi=0;mi<2;++mi)
      #pragma unroll
      for (int r=0;r<4;++r){
        int o = ob + mi*16 + r;
        t1o[mi][r]=t1[o]; t2o[mi][r]=t2[o]; gbo[mi][r]=g1b[o];
      }
    #pragma unroll
    for (int nf=0; nf<4; ++nf){
      int p = pt*64 + nf*16 + lr;
      float mu = meanA[b*PP + p], iv = invA[b*PP + p];
      #pragma unroll
      for (int mi=0;mi<2;++mi){
        unsigned int us[4];
        #pragma unroll
        for (int r=0;r<4;++r){
          float pre = iv*(acc[mi][nf][r] - mu*t1o[mi][r]) + t2o[mi][r] + gbo[mi][r];
          float ge = 0.5f*pre*(1.f + erff(pre*0.70710678118654752f));
          us[r] = f2bf(ge);
        }
        uint2 o2; o2.x = us[0] | (us[1]<<16); o2.y = us[2] | (us[3]<<16);
        *reinterpret_cast<uint2*>(h1bf + ((size_t)(b*PP + p))*64 + (w-2)*32 + mi*16 + ((l>>4)*4)) = o2;
      }
    }
  }
}

// ---------------- scan: fwd + aligned-reverse, IN-PLACE (hs over ug) ----------------
__global__ __launch_bounds__(256) void k_scan(
    float* ugr, float* ugc,
    const float* __restrict__ Arow, const float* __restrict__ Acol)
{
  int g = blockIdx.x*16 + (threadIdx.x >> 4);
  int lane = threadIdx.x & 63;
  int s = lane & 15;
  int base = lane & 48;
  bool isCol = g >= 1024;
  int gg = isCol ? g - 1024 : g;
  int b = gg >> 6, rc = gg & 63;
  float* ug = isCol ? ugc : ugr;
  const float* A  = isCol ? Acol : Arow;
  int p0 = b*PP + (isCol ? rc : rc*64);
  int stride = isCol ? 64 : 1;
  float ac[16];
  #pragma unroll
  for (int i=0;i<16;++i) ac[i] = A[i*16 + s];
  float h[64];
  float hf = 0.f;
  #pragma unroll
  for (int l=0;l<64;++l){
    float gu = ug[((size_t)(p0 + l*stride))*16 + s];
    float t = 0.f;
    #pragma unroll
    for (int i=0;i<16;++i) t += __shfl(hf, base + i, 64) * ac[i];
    hf = t + gu;
    h[l] = hf;
  }
  float hb = 0.f;
  #pragma unroll
  for (int l=63;l>=0;--l){
    float gu = ug[((size_t)(p0 + l*stride))*16 + s];
    float t = 0.f;
    #pragma unroll
    for (int i=0;i<16;++i) t += __shfl(hb, base + i, 64) * ac[i];
    hb = t + gu;
    ug[((size_t)(p0 + l*stride))*16 + s] = h[l] + hb;
  }
}

// ---------------- fused: MFMA skip (K=384) + MFMA gate (K=64) + Wout (VALU) + combine ----
// grid 6144 = (b, ct, pt); 4 waves, wave w owns c-rows ct*64+w*16..+15 x 64 p
__global__ __launch_bounds__(256) void k_fused(
    const float* __restrict__ x, const unsigned short* __restrict__ xbf,
    const unsigned short* __restrict__ WsumBf,
    const unsigned short* __restrict__ h1bf, const unsigned short* __restrict__ g2wBf,
    const float* __restrict__ hsR, const float* __restrict__ hsC,
    const float* __restrict__ WoR, const float* __restrict__ WoC,
    const float* __restrict__ g2b,
    const float* __restrict__ boR, const float* __restrict__ bsR,
    const float* __restrict__ boC, const float* __restrict__ bsC,
    float* __restrict__ outp)
{
  int bid = blockIdx.x;
  int pt = bid & 63; int ct = (bid >> 6) % 6; int b = bid / 384;
  int t = threadIdx.x;
  int w = t >> 6, l = t & 63;
  int lr = l & 15, kb8 = (l >> 4) * 8;
  int c0 = ct*64;
  __shared__ float hsRt[64][17], hsCt[64][17];
  __shared__ float woRt[64][17], woCt[64][17];

  // stage phase-C data (no dependence on GEMMs; single barrier after)
  const float* hsRb = hsR + ((size_t)(b*PP) + pt*64)*16;
  const float* hsCb = hsC + ((size_t)(b*PP) + pt*64)*16;
  #pragma unroll
  for (int r=0;r<4;++r){
    int idx = r*256 + t; int p = idx >> 4, s = idx & 15;
    hsRt[p][s] = hsRb[idx]; hsCt[p][s] = hsCb[idx];
    woRt[p][s] = WoR[(size_t)(c0+p)*16 + s];
    woCt[p][s] = WoC[(size_t)(c0+p)*16 + s];
  }

  // ---- phase A: skip MFMA, K=384 ----
  f32x4 accS[4] = {};
  {
    const unsigned short* wbase = WsumBf + (size_t)(c0 + w*16 + lr)*CCH + kb8;
    const unsigned short* xbase = xbf + ((size_t)(b*PP + pt*64 + lr))*CCH + kb8;
    #pragma unroll
    for (int ks = 0; ks < 12; ++ks) {
      int k0 = ks*32;
      short8 a = *(const short8*)(wbase + k0);
      #pragma unroll
      for (int nf=0; nf<4; ++nf){
        short8 bv = *(const short8*)(xbase + (size_t)nf*16*CCH + k0);
        accS[nf] = __builtin_amdgcn_mfma_f32_16x16x32_bf16(a, bv, accS[nf], 0,0,0);
      }
    }
  }
  // ---- phase B: gate MFMA, K=64 ----
  f32x4 gac[4] = {};
  {
    const unsigned short* wbase = g2wBf + (size_t)(c0 + w*16 + lr)*64 + kb8;
    const unsigned short* hbase = h1bf + ((size_t)(b*PP + pt*64 + lr))*64 + kb8;
    #pragma unroll
    for (int ks = 0; ks < 2; ++ks) {
      int k0 = ks*32;
      short8 a = *(const short8*)(wbase + k0);
      #pragma unroll
      for (int nf=0; nf<4; ++nf){
        short8 bv = *(const short8*)(hbase + (size_t)nf*16*64 + k0);
        gac[nf] = __builtin_amdgcn_mfma_f32_16x16x32_bf16(a, bv, gac[nf], 0,0,0);
      }
    }
  }
  // ---- phase C: Wout contraction on VALU (K=2x16) ----
  __syncthreads();
  float yac[4][4] = {};   // [nf][r]
  int crow = w*16 + ((l>>4)*4);
  #pragma unroll
  for (int s=0;s<16;++s){
    float wr[4], wc[4];
    #pragma unroll
    for (int r=0;r<4;++r){ wr[r]=woRt[crow+r][s]; wc[r]=woCt[crow+r][s]; }
    #pragma unroll
    for (int nf=0;nf<4;++nf){
      float hr = hsRt[nf*16 + lr][s];
      float hc = hsCt[nf*16 + lr][s];
      #pragma unroll
      for (int r=0;r<4;++r) yac[nf][r] += wr[r]*hr + wc[r]*hc;
    }
  }
  // ---- epilogue ----
  float cb[4], gb[4];
  #pragma unroll
  for (int r=0;r<4;++r){
    int c = c0 + crow + r;
    cb[r] = 2.f*(boR[c]+bsR[c]+boC[c]+bsC[c]);
    gb[r] = g2b[c];
  }
  #pragma unroll
  for (int nf=0;nf<4;++nf){
    #pragma unroll
    for (int r=0;r<4;++r){
      int c = c0 + crow + r;
      size_t addr = ((size_t)(b*CCH + c))*PP + pt*64 + nf*16 + lr;
      float xv = x[addr];
      float y = 0.25f*(yac[nf][r] + 2.f*accS[nf][r] + cb[r]);
      float gt = sigmoidf_(gac[nf][r] + gb[r]);
      outp[addr] = gt*y + (1.f-gt)*xv;
    }
  }
}

extern "C" void kernel_launch(void* const* d_in, const int* in_sizes, int n_in,
                              void* d_out, int out_size, void* d_ws, size_t ws_size,
                              hipStream_t stream)
{
  const float* x    = (const float*)d_in[0];
  const float* rAl  = (const float*)d_in[1];
  const float* rU   = (const float*)d_in[2];
  const float* rV   = (const float*)d_in[3];
  const float* rWin = (const float*)d_in[4];
  const float* rbin = (const float*)d_in[5];
  const float* rWg  = (const float*)d_in[6];
  const float* rbg  = (const float*)d_in[7];
  const float* rWo  = (const float*)d_in[8];
  const float* rbo  = (const float*)d_in[9];
  const float* rWs  = (const float*)d_in[10];
  const float* rbs  = (const float*)d_in[11];
  const float* cAl  = (const float*)d_in[12];
  const float* cU   = (const float*)d_in[13];
  const float* cV   = (const float*)d_in[14];
  const float* cWin = (const float*)d_in[15];
  const float* cbin = (const float*)d_in[16];
  const float* cWg  = (const float*)d_in[17];
  const float* cbg  = (const float*)d_in[18];
  const float* cWo  = (const float*)d_in[19];
  const float* cbo  = (const float*)d_in[20];
  const float* cWs  = (const float*)d_in[21];
  const float* cbs  = (const float*)d_in[22];
  const float* g1w  = (const float*)d_in[23];
  const float* g1b  = (const float*)d_in[24];
  const float* g2w  = (const float*)d_in[25];
  const float* g2b  = (const float*)d_in[26];
  const float* nw   = (const float*)d_in[27];
  const float* nb   = (const float*)d_in[28];

  float* ws   = (float*)d_ws;
  float* ugr  = ws;                    // 1048576 (B,P,16) -> becomes hsR in-place
  float* ugc  = ugr + 1048576;         // 1048576 -> hsC
  float* meanA= ugc + 1048576;         // 65536
  float* invA = meanA + 65536;         // 65536
  float* Arow = invA + 65536;          // 256
  float* Acol = Arow + 256;            // 256
  float* t1   = Acol + 256;            // 64
  float* t2   = t1 + 64;               // 64
  unsigned short* xbf    = (unsigned short*)(t2 + 64);   // 16*4096*384 = 25165824
  unsigned short* h1bf   = xbf + (size_t)25165824;       // 16*4096*64  = 4194304
  unsigned short* WsumBf = h1bf + (size_t)4194304;       // 147456
  unsigned short* WcatBf = WsumBf + 147456;              // 49152
  unsigned short* g2wBf  = WcatBf + 49152;               // 24576
  float* outp = (float*)d_out;

  k_prep<<<865, 256, 0, stream>>>(rAl,rU,rV,cAl,cU,cV,rWs,cWs,
                                  rWin,rWg,cWin,cWg,g1w,nw,nb,g2w,
                                  Arow,Acol,WsumBf,WcatBf,g2wBf,t1,t2);
  k_xpose<<<1024, 256, 0, stream>>>(x, xbf, meanA, invA);
  k_front<<<1024, 256, 0, stream>>>(xbf, WcatBf, rbin, rbg, cbin, cbg,
                                    meanA, invA, t1, t2, g1b, ugr, ugc, h1bf);
  k_scan<<<128, 256, 0, stream>>>(ugr, ugc, Arow, Acol);
  k_fused<<<6144, 256, 0, stream>>>(x, xbf, WsumBf, h1bf, g2wBf,
                                    ugr, ugc, rWo, cWo, g2b,
                                    rbo, rbs, cbo, cbs, outp);
}

// Round 4
// 277.544 us; speedup vs baseline: 2.8159x; 1.2628x over previous
//
#include <hip/hip_runtime.h>
#include <hip/hip_bf16.h>
#include <math.h>

#define PP 4096      // H*W
#define CCH 384      // channels
#define NB 16        // batch

using short8 = __attribute__((ext_vector_type(8))) short;
using f32x4  = __attribute__((ext_vector_type(4))) float;

__device__ __forceinline__ float sigmoidf_(float v){ return 1.f/(1.f+expf(-v)); }
__device__ __forceinline__ unsigned int f2bf(float f){
  __hip_bfloat16 h = __float2bfloat16(f);
  return (unsigned int)*reinterpret_cast<unsigned short*>(&h);
}
__device__ __forceinline__ void gload_lds16(const void* g, void* l){
  __builtin_amdgcn_global_load_lds(
      (const __attribute__((address_space(1))) unsigned int*)g,
      (__attribute__((address_space(3))) unsigned int*)l, 16, 0, 0);
}

// ---------------- prep: A matrices, bf16 weights, t1/t2 ----------------
// grid 865: [0,576) WsumBf; [576,768) WcatBf; [768,864) g2wBf; 864: A + t1/t2
__global__ __launch_bounds__(256) void k_prep(
    const float* __restrict__ rAl, const float* __restrict__ rU, const float* __restrict__ rV,
    const float* __restrict__ cAl, const float* __restrict__ cU, const float* __restrict__ cV,
    const float* __restrict__ rWs, const float* __restrict__ cWs,
    const float* __restrict__ WinR, const float* __restrict__ WgR,
    const float* __restrict__ WinC, const float* __restrict__ WgC,
    const float* __restrict__ g1w, const float* __restrict__ nw, const float* __restrict__ nb,
    const float* __restrict__ g2w,
    float* __restrict__ Arow, float* __restrict__ Acol,
    unsigned short* __restrict__ WsumBf, unsigned short* __restrict__ WcatBf,
    unsigned short* __restrict__ g2wBf,
    float* __restrict__ t1, float* __restrict__ t2)
{
  int bid = blockIdx.x, tid = threadIdx.x;
  if (bid < 576) {
    int idx = bid*256 + tid;
    WsumBf[idx] = (unsigned short)f2bf(rWs[idx] + cWs[idx]);
  } else if (bid < 768) {
    int idx = (bid-576)*256 + tid;
    int row = idx / CCH, col = idx - row*CCH;
    float v;
    if      (row < 16)  v = WinR[row*CCH + col];
    else if (row < 32)  v = WgR [(row-16)*CCH + col];
    else if (row < 48)  v = WinC[(row-32)*CCH + col];
    else if (row < 64)  v = WgC [(row-48)*CCH + col];
    else                v = g1w[(row-64)*CCH + col]*nw[col];
    WcatBf[idx] = (unsigned short)f2bf(v);
  } else if (bid < 864) {
    int idx = (bid-768)*256 + tid;
    g2wBf[idx] = (unsigned short)f2bf(g2w[idx]);
  } else {
    {
      int i = tid >> 4, j = tid & 15;
      float sr = 0.f, sc = 0.f;
      #pragma unroll
      for (int r=0;r<8;++r){ sr += rV[i*8+r]*rU[j*8+r]; sc += cV[i*8+r]*cU[j*8+r]; }
      if (i==j){ sr += sigmoidf_(rAl[i]); sc += sigmoidf_(cAl[i]); }
      Arow[tid] = sr; Acol[tid] = sc;
    }
    if (tid < 64) {
      float s1=0.f, s2=0.f;
      for (int c=0;c<CCH;++c){ s1 += g1w[tid*CCH+c]*nw[c]; s2 += nb[c]*g1w[tid*CCH+c]; }
      t1[tid]=s1; t2[tid]=s2;
    }
  }
}

// ---------------- xpose: x (b,c,p) -> xbf (b,p,c) bf16; per-position mean/invstd ----
__global__ __launch_bounds__(256) void k_xpose(
    const float* __restrict__ x, unsigned short* __restrict__ xbf,
    float* __restrict__ meanA, float* __restrict__ invA)
{
  int b = blockIdx.x >> 6, pt = blockIdx.x & 63;
  int t = threadIdx.x;
  int pl = t & 63, g4 = t >> 6;
  __shared__ float tile[64][65];
  float sx = 0.f, sx2 = 0.f;
  const float* xb = x + (size_t)b*CCH*PP + pt*64;
  int pw = t >> 2, q = t & 3;
  unsigned short* xo = xbf + ((size_t)(b*PP + pt*64 + pw))*CCH;
  for (int cc = 0; cc < 6; ++cc) {
    __syncthreads();
    #pragma unroll
    for (int r=0;r<16;++r)
      tile[r*4+g4][pl] = xb[(size_t)(cc*64 + r*4 + g4)*PP + pl];
    __syncthreads();
    #pragma unroll
    for (int j=0;j<16;++j){ float v = tile[g4*16+j][pl]; sx += v; sx2 += v*v; }
    #pragma unroll
    for (int j=0;j<4;++j){
      unsigned int u0 = f2bf(tile[q*16+j*4+0][pw]);
      unsigned int u1 = f2bf(tile[q*16+j*4+1][pw]);
      unsigned int u2 = f2bf(tile[q*16+j*4+2][pw]);
      unsigned int u3 = f2bf(tile[q*16+j*4+3][pw]);
      uint2 o; o.x = u0 | (u1<<16); o.y = u2 | (u3<<16);
      *reinterpret_cast<uint2*>(xo + cc*64 + q*16 + j*4) = o;
    }
  }
  __syncthreads();
  float* red = &tile[0][0];
  red[g4*64 + pl] = sx;
  red[256 + g4*64 + pl] = sx2;
  __syncthreads();
  if (t < 64) {
    float s1 = red[t] + red[64+t] + red[128+t] + red[192+t];
    float s2 = red[256+t] + red[320+t] + red[384+t] + red[448+t];
    float mu = s1 * (1.f/CCH);
    float var = s2 * (1.f/CCH) - mu*mu;
    meanA[b*PP + pt*64 + t] = mu;
    invA [b*PP + pt*64 + t] = rsqrtf(var + 1e-6f);
  }
}

// ---------------- front: MFMA GEMM, 128 outs = [uR gR uC gC h1pre(64)] x K=384 ----
__global__ __launch_bounds__(256) void k_front(
    const unsigned short* __restrict__ xbf, const unsigned short* __restrict__ WcatBf,
    const float* __restrict__ binR, const float* __restrict__ bgR,
    const float* __restrict__ binC, const float* __restrict__ bgC,
    const float* __restrict__ meanA, const float* __restrict__ invA,
    const float* __restrict__ t1, const float* __restrict__ t2,
    const float* __restrict__ g1b,
    float* __restrict__ ugr, float* __restrict__ ugc,
    unsigned short* __restrict__ h1bf)
{
  int b = blockIdx.x >> 6, pt = blockIdx.x & 63;
  int t = threadIdx.x;
  int w = t >> 6, l = t & 63;
  int lr = l & 15, kb8 = (l >> 4) * 8;
  f32x4 acc[2][4] = {};
  const unsigned short* wbase0 = WcatBf + (size_t)(w*32 + lr)*CCH + kb8;
  const unsigned short* wbase1 = wbase0 + 16*CCH;
  const unsigned short* xbase  = xbf + ((size_t)(b*PP + pt*64 + lr))*CCH + kb8;
  #pragma unroll
  for (int ks = 0; ks < 12; ++ks) {
    int k0 = ks*32;
    short8 a0 = *(const short8*)(wbase0 + k0);
    short8 a1 = *(const short8*)(wbase1 + k0);
    short8 bv[4];
    #pragma unroll
    for (int nf=0; nf<4; ++nf)
      bv[nf] = *(const short8*)(xbase + (size_t)nf*16*CCH + k0);
    #pragma unroll
    for (int nf=0; nf<4; ++nf){
      acc[0][nf] = __builtin_amdgcn_mfma_f32_16x16x32_bf16(a0, bv[nf], acc[0][nf], 0,0,0);
      acc[1][nf] = __builtin_amdgcn_mfma_f32_16x16x32_bf16(a1, bv[nf], acc[1][nf], 0,0,0);
    }
  }
  if (w < 2) {
    const float* bu = w ? binC : binR;
    const float* bg = w ? bgC  : bgR;
    float* dst = w ? ugc : ugr;
    float bus[4], bgs[4];
    #pragma unroll
    for (int r=0;r<4;++r){ int s = (l>>4)*4 + r; bus[r]=bu[s]; bgs[r]=bg[s]; }
    #pragma unroll
    for (int nf=0; nf<4; ++nf){
      size_t pbase = ((size_t)(b*PP + pt*64 + nf*16 + lr))*16;
      #pragma unroll
      for (int r=0;r<4;++r){
        int s = (l>>4)*4 + r;
        float u = acc[0][nf][r] + bus[r];
        float g = sigmoidf_(acc[1][nf][r] + bgs[r]);
        dst[pbase + s] = u*g;
      }
    }
  } else {
    int ob = (w-2)*32 + ((l>>4)*4);
    float t1o[2][4], t2o[2][4], gbo[2][4];
    #pragma unroll
    for (int mi=0;mi<2;++mi)
      #pragma unroll
      for (int r=0;r<4;++r){
        int o = ob + mi*16 + r;
        t1o[mi][r]=t1[o]; t2o[mi][r]=t2[o]; gbo[mi][r]=g1b[o];
      }
    #pragma unroll
    for (int nf=0; nf<4; ++nf){
      int p = pt*64 + nf*16 + lr;
      float mu = meanA[b*PP + p], iv = invA[b*PP + p];
      #pragma unroll
      for (int mi=0;mi<2;++mi){
        unsigned int us[4];
        #pragma unroll
        for (int r=0;r<4;++r){
          float pre = iv*(acc[mi][nf][r] - mu*t1o[mi][r]) + t2o[mi][r] + gbo[mi][r];
          float ge = 0.5f*pre*(1.f + erff(pre*0.70710678118654752f));
          us[r] = f2bf(ge);
        }
        uint2 o2; o2.x = us[0] | (us[1]<<16); o2.y = us[2] | (us[3]<<16);
        *reinterpret_cast<uint2*>(h1bf + ((size_t)(b*PP + p))*64 + (w-2)*32 + mi*16 + ((l>>4)*4)) = o2;
      }
    }
  }
}

// ---------------- scan: fwd + aligned-reverse, IN-PLACE (hs over ug) ----------------
__global__ __launch_bounds__(256) void k_scan(
    float* ugr, float* ugc,
    const float* __restrict__ Arow, const float* __restrict__ Acol)
{
  int g = blockIdx.x*16 + (threadIdx.x >> 4);
  int lane = threadIdx.x & 63;
  int s = lane & 15;
  int base = lane & 48;
  bool isCol = g >= 1024;
  int gg = isCol ? g - 1024 : g;
  int b = gg >> 6, rc = gg & 63;
  float* ug = isCol ? ugc : ugr;
  const float* A  = isCol ? Acol : Arow;
  int p0 = b*PP + (isCol ? rc : rc*64);
  int stride = isCol ? 64 : 1;
  float ac[16];
  #pragma unroll
  for (int i=0;i<16;++i) ac[i] = A[i*16 + s];
  float h[64];
  float hf = 0.f;
  #pragma unroll
  for (int l=0;l<64;++l){
    float gu = ug[((size_t)(p0 + l*stride))*16 + s];
    float t = 0.f;
    #pragma unroll
    for (int i=0;i<16;++i) t += __shfl(hf, base + i, 64) * ac[i];
    hf = t + gu;
    h[l] = hf;
  }
  float hb = 0.f;
  #pragma unroll
  for (int l=63;l>=0;--l){
    float gu = ug[((size_t)(p0 + l*stride))*16 + s];
    float t = 0.f;
    #pragma unroll
    for (int i=0;i<16;++i) t += __shfl(hb, base + i, 64) * ac[i];
    hb = t + gu;
    ug[((size_t)(p0 + l*stride))*16 + s] = h[l] + hb;
  }
}

// ---------------- fused: LDS-pipelined MFMA skip (K=384) + gate (K=64) + Wout + combine ----
// grid 6144 = (b, ct, pt) with XCD swizzle; 4 waves; wave w owns c-rows ct*64+w*16..+15
// xbf B-tile staged per 64k chunk via global_load_lds, double-buffered, XOR-swizzled.
__global__ __launch_bounds__(256) void k_fused(
    const float* __restrict__ x, const unsigned short* __restrict__ xbf,
    const unsigned short* __restrict__ WsumBf,
    const unsigned short* __restrict__ h1bf, const unsigned short* __restrict__ g2wBf,
    const float* __restrict__ hsR, const float* __restrict__ hsC,
    const float* __restrict__ WoR, const float* __restrict__ WoC,
    const float* __restrict__ g2b,
    const float* __restrict__ boR, const float* __restrict__ bsR,
    const float* __restrict__ boC, const float* __restrict__ bsC,
    float* __restrict__ outp)
{
  // XCD-aware bijective swizzle: 6144 blocks -> 8 chunks of 768 (2 batches each per XCD)
  int obid = blockIdx.x;
  int bid = ((obid & 7) * 768) + (obid >> 3);
  int pt = bid & 63; int ct = (bid >> 6) % 6; int b = bid / 384;
  int t = threadIdx.x;
  int w = t >> 6, l = t & 63;
  int lr = l & 15, qw = l >> 4, kb8 = qw * 8;
  int c0 = ct*64;

  __shared__ unsigned short xt[2][512*8];      // 2 x 8KB: [granule 0..511][8 bf16]
  __shared__ float hsRt[64][17], hsCt[64][17];
  __shared__ float woRt[64][17], woCt[64][17];

  // ---- issue stage of chunk 0 (longest latency first) ----
  const unsigned short* xrow0 = xbf + ((size_t)(b*PP + pt*64))*CCH;
  int g0 = w*128 + l;           // granule for issue 0; +64 for issue 1
  {
    int ga = g0, gb2 = g0 + 64;
    int pa = ga>>3, pb = gb2>>3;
    int ka = ((ga&7) ^ (pa&7))*8, kb = ((gb2&7) ^ (pb&7))*8;
    gload_lds16(xrow0 + (size_t)pa*CCH + 0*64 + ka, &xt[0][(size_t)(w*128)*8]);
    gload_lds16(xrow0 + (size_t)pb*CCH + 0*64 + kb, &xt[0][(size_t)(w*128+64)*8]);
  }

  // ---- gate phase loads (global, independent) ----
  short8 ga_[2], gb_[2][4];
  {
    const unsigned short* wbase = g2wBf + (size_t)(c0 + w*16 + lr)*64 + kb8;
    const unsigned short* hbase = h1bf + ((size_t)(b*PP + pt*64 + lr))*64 + kb8;
    #pragma unroll
    for (int ks=0; ks<2; ++ks){
      ga_[ks] = *(const short8*)(wbase + ks*32);
      #pragma unroll
      for (int nf=0; nf<4; ++nf)
        gb_[ks][nf] = *(const short8*)(hbase + (size_t)nf*16*64 + ks*32);
    }
  }
  // ---- hs/wo tile loads + LDS writes ----
  {
    const float* hsRb = hsR + ((size_t)(b*PP) + pt*64)*16;
    const float* hsCb = hsC + ((size_t)(b*PP) + pt*64)*16;
    #pragma unroll
    for (int r=0;r<4;++r){
      int idx = r*256 + t; int p = idx >> 4, s = idx & 15;
      hsRt[p][s] = hsRb[idx]; hsCt[p][s] = hsCb[idx];
      woRt[p][s] = WoR[(size_t)(c0+p)*16 + s];
      woCt[p][s] = WoC[(size_t)(c0+p)*16 + s];
    }
  }
  // ---- gate MFMAs (operands in regs) ----
  f32x4 gac[4] = {};
  #pragma unroll
  for (int ks=0; ks<2; ++ks)
    #pragma unroll
    for (int nf=0; nf<4; ++nf)
      gac[nf] = __builtin_amdgcn_mfma_f32_16x16x32_bf16(ga_[ks], gb_[ks][nf], gac[nf], 0,0,0);

  // ---- skip-phase A-frag prefetch (chunk 0) ----
  const unsigned short* wbaseS = WsumBf + (size_t)(c0 + w*16 + lr)*CCH + kb8;
  short8 af[2][2];
  af[0][0] = *(const short8*)(wbaseS + 0);
  af[0][1] = *(const short8*)(wbaseS + 32);

  f32x4 accS[4] = {};
  __syncthreads();   // drains vmcnt(0): chunk 0 staged; gate/hs loads done anyway

  // ---- main K loop: 6 chunks of 64, double-buffered ----
  #pragma unroll
  for (int c = 0; c < 6; ++c) {
    int cb = c & 1, nb2 = cb ^ 1;
    if (c < 5) {
      // stage chunk c+1 into other buffer
      int ga = g0, gb2 = g0 + 64;
      int pa = ga>>3, pb = gb2>>3;
      int ka = ((ga&7) ^ (pa&7))*8, kb = ((gb2&7) ^ (pb&7))*8;
      gload_lds16(xrow0 + (size_t)pa*CCH + (c+1)*64 + ka, &xt[nb2][(size_t)(w*128)*8]);
      gload_lds16(xrow0 + (size_t)pb*CCH + (c+1)*64 + kb, &xt[nb2][(size_t)(w*128+64)*8]);
      af[nb2][0] = *(const short8*)(wbaseS + (c+1)*64);
      af[nb2][1] = *(const short8*)(wbaseS + (c+1)*64 + 32);
    }
    // MFMAs on chunk c from xt[cb]
    #pragma unroll
    for (int ks=0; ks<2; ++ks){
      int kg = ks*4 + qw;           // 0..7
      #pragma unroll
      for (int nf=0; nf<4; ++nf){
        int pr = nf*16 + lr;
        int gr = pr*8 + (kg ^ (pr & 7));
        short8 bv = *(const short8*)&xt[cb][(size_t)gr*8];
        accS[nf] = __builtin_amdgcn_mfma_f32_16x16x32_bf16(af[cb][ks], bv, accS[nf], 0,0,0);
      }
    }
    __syncthreads();   // implicit vmcnt(0)+lgkmcnt(0) drain before barrier
  }

  // ---- phase C: Wout contraction on VALU (K=2x16) ----
  float yac[4][4] = {};   // [nf][r]
  int crow = w*16 + ((l>>4)*4);
  #pragma unroll
  for (int s=0;s<16;++s){
    float wr[4], wc[4];
    #pragma unroll
    for (int r=0;r<4;++r){ wr[r]=woRt[crow+r][s]; wc[r]=woCt[crow+r][s]; }
    #pragma unroll
    for (int nf=0;nf<4;++nf){
      float hr = hsRt[nf*16 + lr][s];
      float hc = hsCt[nf*16 + lr][s];
      #pragma unroll
      for (int r=0;r<4;++r) yac[nf][r] += wr[r]*hr + wc[r]*hc;
    }
  }
  // ---- epilogue ----
  float cb4[4], gb4[4];
  #pragma unroll
  for (int r=0;r<4;++r){
    int c = c0 + crow + r;
    cb4[r] = 2.f*(boR[c]+bsR[c]+boC[c]+bsC[c]);
    gb4[r] = g2b[c];
  }
  #pragma unroll
  for (int nf=0;nf<4;++nf){
    #pragma unroll
    for (int r=0;r<4;++r){
      int c = c0 + crow + r;
      size_t addr = ((size_t)(b*CCH + c))*PP + pt*64 + nf*16 + lr;
      float xv = x[addr];
      float y = 0.25f*(yac[nf][r] + 2.f*accS[nf][r] + cb4[r]);
      float gt = sigmoidf_(gac[nf][r] + gb4[r]);
      outp[addr] = gt*y + (1.f-gt)*xv;
    }
  }
}

extern "C" void kernel_launch(void* const* d_in, const int* in_sizes, int n_in,
                              void* d_out, int out_size, void* d_ws, size_t ws_size,
                              hipStream_t stream)
{
  const float* x    = (const float*)d_in[0];
  const float* rAl  = (const float*)d_in[1];
  const float* rU   = (const float*)d_in[2];
  const float* rV   = (const float*)d_in[3];
  const float* rWin = (const float*)d_in[4];
  const float* rbin = (const float*)d_in[5];
  const float* rWg  = (const float*)d_in[6];
  const float* rbg  = (const float*)d_in[7];
  const float* rWo  = (const float*)d_in[8];
  const float* rbo  = (const float*)d_in[9];
  const float* rWs  = (const float*)d_in[10];
  const float* rbs  = (const float*)d_in[11];
  const float* cAl  = (const float*)d_in[12];
  const float* cU   = (const float*)d_in[13];
  const float* cV   = (const float*)d_in[14];
  const float* cWin = (const float*)d_in[15];
  const float* cbin = (const float*)d_in[16];
  const float* cWg  = (const float*)d_in[17];
  const float* cbg  = (const float*)d_in[18];
  const float* cWo  = (const float*)d_in[19];
  const float* cbo  = (const float*)d_in[20];
  const float* cWs  = (const float*)d_in[21];
  const float* cbs  = (const float*)d_in[22];
  const float* g1w  = (const float*)d_in[23];
  const float* g1b  = (const float*)d_in[24];
  const float* g2w  = (const float*)d_in[25];
  const float* g2b  = (const float*)d_in[26];
  const float* nw   = (const float*)d_in[27];
  const float* nb   = (const float*)d_in[28];

  float* ws   = (float*)d_ws;
  float* ugr  = ws;                    // 1048576 (B,P,16) -> becomes hsR in-place
  float* ugc  = ugr + 1048576;         // 1048576 -> hsC
  float* meanA= ugc + 1048576;         // 65536
  float* invA = meanA + 65536;         // 65536
  float* Arow = invA + 65536;          // 256
  float* Acol = Arow + 256;            // 256
  float* t1   = Acol + 256;            // 64
  float* t2   = t1 + 64;               // 64
  unsigned short* xbf    = (unsigned short*)(t2 + 64);   // 16*4096*384 = 25165824
  unsigned short* h1bf   = xbf + (size_t)25165824;       // 16*4096*64  = 4194304
  unsigned short* WsumBf = h1bf + (size_t)4194304;       // 147456
  unsigned short* WcatBf = WsumBf + 147456;              // 49152
  unsigned short* g2wBf  = WcatBf + 49152;               // 24576
  float* outp = (float*)d_out;

  k_prep<<<865, 256, 0, stream>>>(rAl,rU,rV,cAl,cU,cV,rWs,cWs,
                                  rWin,rWg,cWin,cWg,g1w,nw,nb,g2w,
                                  Arow,Acol,WsumBf,WcatBf,g2wBf,t1,t2);
  k_xpose<<<1024, 256, 0, stream>>>(x, xbf, meanA, invA);
  k_front<<<1024, 256, 0, stream>>>(xbf, WcatBf, rbin, rbg, cbin, cbg,
                                    meanA, invA, t1, t2, g1b, ugr, ugc, h1bf);
  k_scan<<<128, 256, 0, stream>>>(ugr, ugc, Arow, Acol);
  k_fused<<<6144, 256, 0, stream>>>(x, xbf, WsumBf, h1bf, g2wBf,
                                    ugr, ugc, rWo, cWo, g2b,
                                    rbo, rbs, cbo, cbs, outp);
}

// Round 5
// 198.929 us; speedup vs baseline: 3.9287x; 1.3952x over previous
//
#include <hip/hip_runtime.h>
#include <hip/hip_bf16.h>
#include <math.h>

#define PP 4096      // H*W
#define CCH 384      // channels
#define NB 16        // batch

using short8 = __attribute__((ext_vector_type(8))) short;
using f32x4  = __attribute__((ext_vector_type(4))) float;

__device__ __forceinline__ float sigmoidf_(float v){ return 1.f/(1.f+expf(-v)); }
__device__ __forceinline__ unsigned int f2bf(float f){
  __hip_bfloat16 h = __float2bfloat16(f);
  return (unsigned int)*reinterpret_cast<unsigned short*>(&h);
}
__device__ __forceinline__ void gload_lds16(const void* g, void* l){
  __builtin_amdgcn_global_load_lds(
      (const __attribute__((address_space(1))) unsigned int*)g,
      (__attribute__((address_space(3))) unsigned int*)l, 16, 0, 0);
}

// ---------------- prep: A matrices, bf16 weights, t1/t2 ----------------
// grid 913: [0,576) WsumBf; [576,768) WcatBf; [768,864) g2wBf; [864,912) WocatBf; 912: A+t1/t2
__global__ __launch_bounds__(256) void k_prep(
    const float* __restrict__ rAl, const float* __restrict__ rU, const float* __restrict__ rV,
    const float* __restrict__ cAl, const float* __restrict__ cU, const float* __restrict__ cV,
    const float* __restrict__ rWs, const float* __restrict__ cWs,
    const float* __restrict__ WinR, const float* __restrict__ WgR,
    const float* __restrict__ WinC, const float* __restrict__ WgC,
    const float* __restrict__ g1w, const float* __restrict__ nw, const float* __restrict__ nb,
    const float* __restrict__ g2w,
    const float* __restrict__ WoR, const float* __restrict__ WoC,
    float* __restrict__ Arow, float* __restrict__ Acol,
    unsigned short* __restrict__ WsumBf, unsigned short* __restrict__ WcatBf,
    unsigned short* __restrict__ g2wBf, unsigned short* __restrict__ WocatBf,
    float* __restrict__ t1, float* __restrict__ t2)
{
  int bid = blockIdx.x, tid = threadIdx.x;
  if (bid < 576) {
    int idx = bid*256 + tid;
    WsumBf[idx] = (unsigned short)f2bf(rWs[idx] + cWs[idx]);
  } else if (bid < 768) {
    int idx = (bid-576)*256 + tid;
    int row = idx / CCH, col = idx - row*CCH;
    float v;
    if      (row < 16)  v = WinR[row*CCH + col];
    else if (row < 32)  v = WgR [(row-16)*CCH + col];
    else if (row < 48)  v = WinC[(row-32)*CCH + col];
    else if (row < 64)  v = WgC [(row-48)*CCH + col];
    else                v = g1w[(row-64)*CCH + col]*nw[col];
    WcatBf[idx] = (unsigned short)f2bf(v);
  } else if (bid < 864) {
    int idx = (bid-768)*256 + tid;
    g2wBf[idx] = (unsigned short)f2bf(g2w[idx]);
  } else if (bid < 912) {
    int idx = (bid-864)*256 + tid;   // [0, 12288)
    int c = idx >> 5, k = idx & 31;
    float v = (k < 16) ? WoR[c*16 + k] : WoC[c*16 + (k-16)];
    WocatBf[idx] = (unsigned short)f2bf(v);
  } else {
    {
      int i = tid >> 4, j = tid & 15;
      float sr = 0.f, sc = 0.f;
      #pragma unroll
      for (int r=0;r<8;++r){ sr += rV[i*8+r]*rU[j*8+r]; sc += cV[i*8+r]*cU[j*8+r]; }
      if (i==j){ sr += sigmoidf_(rAl[i]); sc += sigmoidf_(cAl[i]); }
      Arow[tid] = sr; Acol[tid] = sc;
    }
    if (tid < 64) {
      float s1=0.f, s2=0.f;
      for (int c=0;c<CCH;++c){ s1 += g1w[tid*CCH+c]*nw[c]; s2 += nb[c]*g1w[tid*CCH+c]; }
      t1[tid]=s1; t2[tid]=s2;
    }
  }
}

// ---------------- xf: transpose + bf16 + stats + front MFMA GEMM, all in one ----------------
// grid 1024 = (b, pt); block 256, 4 waves.
// Per chunk (64 c): coalesced fp32 load -> bf16 pack -> swizzled LDS tile (p,k) ->
//   {front MFMAs (B from LDS), coalesced xbf global write (from LDS)}.
// Outputs: xbf (b,p,c) bf16; ugr/ugc (B,P,16) fp32; h1bf (b,p,64) bf16.
__global__ __launch_bounds__(256) void k_xf(
    const float* __restrict__ x, const unsigned short* __restrict__ WcatBf,
    const float* __restrict__ binR, const float* __restrict__ bgR,
    const float* __restrict__ binC, const float* __restrict__ bgC,
    const float* __restrict__ t1, const float* __restrict__ t2,
    const float* __restrict__ g1b,
    unsigned short* __restrict__ xbf,
    float* __restrict__ ugr, float* __restrict__ ugc,
    unsigned short* __restrict__ h1bf)
{
  int b = blockIdx.x >> 6, pt = blockIdx.x & 63;
  int t = threadIdx.x;
  int w = t >> 6, l = t & 63;
  int lr = l & 15, kq = l >> 4, kb8 = kq*8;
  int pl = t & 63, g4 = w;           // load mapping: thread holds c = cc*64 + g4*16 + j at p = pl

  __shared__ unsigned short xtb[64*64];   // granule(p,kg) at p*8 + (kg ^ (p&7)); 16B granules
  __shared__ float red[512];
  __shared__ float meanS[64], invS[64];

  const float* xb = x + (size_t)b*CCH*PP + pt*64;
  f32x4 acc[2][4] = {};
  float sx = 0.f, sx2 = 0.f;

  // prefetch chunk 0
  float xv[16];
  #pragma unroll
  for (int j=0;j<16;++j) xv[j] = xb[(size_t)(g4*16 + j)*PP + pl];

  const unsigned short* wrow0 = WcatBf + (size_t)(w*32 + lr)*CCH + kb8;
  const unsigned short* wrow1 = wrow0 + 16*CCH;
  unsigned short* xgo = xbf + ((size_t)(b*PP + pt*64))*CCH;

  #pragma unroll
  for (int cc=0; cc<6; ++cc) {
    // stats + convert current chunk
    unsigned int pk[8];
    #pragma unroll
    for (int j=0;j<16;++j){ sx += xv[j]; sx2 += xv[j]*xv[j]; }
    #pragma unroll
    for (int j=0;j<8;++j) pk[j] = f2bf(xv[2*j]) | (f2bf(xv[2*j+1])<<16);
    __syncthreads();   // previous chunk's LDS reads complete
    {
      int kg0 = g4*2, kg1 = g4*2+1;
      uint4 v0 = make_uint4(pk[0],pk[1],pk[2],pk[3]);
      uint4 v1 = make_uint4(pk[4],pk[5],pk[6],pk[7]);
      *(uint4*)&xtb[(size_t)(pl*8 + (kg0 ^ (pl&7)))*8] = v0;
      *(uint4*)&xtb[(size_t)(pl*8 + (kg1 ^ (pl&7)))*8] = v1;
    }
    // prefetch next chunk (overlaps with MFMA phase after barrier)
    if (cc < 5) {
      #pragma unroll
      for (int j=0;j<16;++j) xv[j] = xb[(size_t)((cc+1)*64 + g4*16 + j)*PP + pl];
    }
    // A-frags for this chunk (L2-hot)
    short8 a0k0 = *(const short8*)(wrow0 + cc*64);
    short8 a0k1 = *(const short8*)(wrow0 + cc*64 + 32);
    short8 a1k0 = *(const short8*)(wrow1 + cc*64);
    short8 a1k1 = *(const short8*)(wrow1 + cc*64 + 32);
    __syncthreads();   // xtb chunk cc visible
    // front MFMAs: B-frag rows p = nf*16+lr, k-granules (ks*4+kq)
    #pragma unroll
    for (int ks=0; ks<2; ++ks){
      int kg = ks*4 + kq;
      #pragma unroll
      for (int nf=0; nf<4; ++nf){
        int pr = nf*16 + lr;
        short8 bv = *(const short8*)&xtb[(size_t)(pr*8 + (kg ^ (pr&7)))*8];
        acc[0][nf] = __builtin_amdgcn_mfma_f32_16x16x32_bf16(ks? a0k1:a0k0, bv, acc[0][nf], 0,0,0);
        acc[1][nf] = __builtin_amdgcn_mfma_f32_16x16x32_bf16(ks? a1k1:a1k0, bv, acc[1][nf], 0,0,0);
      }
    }
    // coalesced xbf global write from LDS: 8 lanes cover 128B of one p-row
    #pragma unroll
    for (int it=0; it<2; ++it){
      int p2 = 32*it + (t>>3), kg2 = t & 7;
      uint4 v = *(const uint4*)&xtb[(size_t)(p2*8 + (kg2 ^ (p2&7)))*8];
      *(uint4*)&xgo[(size_t)p2*CCH + cc*64 + kg2*8] = v;
    }
  }

  // stats reduction -> meanS/invS
  __syncthreads();
  red[g4*64 + pl] = sx;
  red[256 + g4*64 + pl] = sx2;
  __syncthreads();
  if (t < 64) {
    float s1 = red[t] + red[64+t] + red[128+t] + red[192+t];
    float s2 = red[256+t] + red[320+t] + red[384+t] + red[448+t];
    float mu = s1 * (1.f/CCH);
    float var = s2 * (1.f/CCH) - mu*mu;
    meanS[t] = mu;
    invS[t]  = rsqrtf(var + 1e-6f);
  }
  __syncthreads();

  if (w < 2) {
    // ug epilogue: m0 -> u, m1 -> g; s = kq*4 + r
    const float* bu = w ? binC : binR;
    const float* bg = w ? bgC  : bgR;
    float* dst = w ? ugc : ugr;
    float bus[4], bgs[4];
    #pragma unroll
    for (int r=0;r<4;++r){ int s = kq*4 + r; bus[r]=bu[s]; bgs[r]=bg[s]; }
    #pragma unroll
    for (int nf=0; nf<4; ++nf){
      size_t pbase = ((size_t)(b*PP + pt*64 + nf*16 + lr))*16;
      #pragma unroll
      for (int r=0;r<4;++r){
        int s = kq*4 + r;
        float u = acc[0][nf][r] + bus[r];
        float g = sigmoidf_(acc[1][nf][r] + bgs[r]);
        dst[pbase + s] = u*g;
      }
    }
  } else {
    // h1 epilogue: o = (w-2)*32 + mi*16 + kq*4 + r
    int ob = (w-2)*32 + kq*4;
    float t1o[2][4], t2o[2][4], gbo[2][4];
    #pragma unroll
    for (int mi=0;mi<2;++mi)
      #pragma unroll
      for (int r=0;r<4;++r){
        int o = ob + mi*16 + r;
        t1o[mi][r]=t1[o]; t2o[mi][r]=t2[o]; gbo[mi][r]=g1b[o];
      }
    #pragma unroll
    for (int nf=0; nf<4; ++nf){
      int pLoc = nf*16 + lr;
      float mu = meanS[pLoc], iv = invS[pLoc];
      #pragma unroll
      for (int mi=0;mi<2;++mi){
        unsigned int us[4];
        #pragma unroll
        for (int r=0;r<4;++r){
          float pre = iv*(acc[mi][nf][r] - mu*t1o[mi][r]) + t2o[mi][r] + gbo[mi][r];
          float ge = 0.5f*pre*(1.f + erff(pre*0.70710678118654752f));
          us[r] = f2bf(ge);
        }
        uint2 o2; o2.x = us[0] | (us[1]<<16); o2.y = us[2] | (us[3]<<16);
        *reinterpret_cast<uint2*>(h1bf + ((size_t)(b*PP + pt*64 + pLoc))*64 + (w-2)*32 + mi*16 + kq*4) = o2;
      }
    }
  }
}

// ---------------- scan: fwd + aligned-reverse; writes hscat bf16 (B,P,32)=[hsR|hsC] ----------
__global__ __launch_bounds__(256) void k_scan(
    const float* __restrict__ ugr, const float* __restrict__ ugc,
    const float* __restrict__ Arow, const float* __restrict__ Acol,
    unsigned short* __restrict__ hscat)
{
  int g = blockIdx.x*16 + (threadIdx.x >> 4);
  int lane = threadIdx.x & 63;
  int s = lane & 15;
  int base = lane & 48;
  bool isCol = g >= 1024;
  int gg = isCol ? g - 1024 : g;
  int b = gg >> 6, rc = gg & 63;
  const float* ug = isCol ? ugc : ugr;
  const float* A  = isCol ? Acol : Arow;
  int off = isCol ? 16 : 0;
  int p0 = b*PP + (isCol ? rc : rc*64);
  int stride = isCol ? 64 : 1;
  float ac[16];
  #pragma unroll
  for (int i=0;i<16;++i) ac[i] = A[i*16 + s];
  float h[64];
  float hf = 0.f;
  #pragma unroll
  for (int l=0;l<64;++l){
    float gu = ug[((size_t)(p0 + l*stride))*16 + s];
    float t = 0.f;
    #pragma unroll
    for (int i=0;i<16;++i) t += __shfl(hf, base + i, 64) * ac[i];
    hf = t + gu;
    h[l] = hf;
  }
  float hb = 0.f;
  #pragma unroll
  for (int l=63;l>=0;--l){
    float gu = ug[((size_t)(p0 + l*stride))*16 + s];
    float t = 0.f;
    #pragma unroll
    for (int i=0;i<16;++i) t += __shfl(hb, base + i, 64) * ac[i];
    hb = t + gu;
    hscat[((size_t)(p0 + l*stride))*32 + off + s] = (unsigned short)f2bf(h[l] + hb);
  }
}

// ---------------- fused: 128 c-rows/block; MFMA skip(K=384)+gate(K=64)+Wout(K=32)+combine ----
// grid 3072 = (b, ct(3), pt) with XCD swizzle; 4 waves; wave w: rows c0+{0,64}+w*16..+15
__global__ __launch_bounds__(256) void k_fused(
    const float* __restrict__ x, const unsigned short* __restrict__ xbf,
    const unsigned short* __restrict__ WsumBf,
    const unsigned short* __restrict__ h1bf, const unsigned short* __restrict__ g2wBf,
    const unsigned short* __restrict__ hscat, const unsigned short* __restrict__ WocatBf,
    const float* __restrict__ g2b,
    const float* __restrict__ boR, const float* __restrict__ bsR,
    const float* __restrict__ boC, const float* __restrict__ bsC,
    float* __restrict__ outp)
{
  // XCD-aware bijective swizzle: 3072 = 8 * 384
  int obid = blockIdx.x;
  int bid = ((obid & 7) * 384) + (obid >> 3);
  int pt = bid & 63; int ct = (bid >> 6) % 3; int b = bid / 192;
  int t = threadIdx.x;
  int w = t >> 6, l = t & 63;
  int lr = l & 15, kq = l >> 4, kb8 = kq * 8;
  int c0 = ct*128;

  __shared__ unsigned short xt[2][512*8];      // 2 x 8KB B-tile chunks

  // ---- issue stage of chunk 0 ----
  const unsigned short* xrow0 = xbf + ((size_t)(b*PP + pt*64))*CCH;
  int g0 = w*128 + l;
  {
    int ga = g0, gb2 = g0 + 64;
    int pa = ga>>3, pb = gb2>>3;
    int ka = ((ga&7) ^ (pa&7))*8, kb = ((gb2&7) ^ (pb&7))*8;
    gload_lds16(xrow0 + (size_t)pa*CCH + ka, &xt[0][(size_t)(w*128)*8]);
    gload_lds16(xrow0 + (size_t)pb*CCH + kb, &xt[0][(size_t)(w*128+64)*8]);
  }

  // ---- gate phase: K=64, 2 m-frags (operands from global, hides stage-0 latency) ----
  f32x4 gac[2][4] = {};
  {
    const unsigned short* hbase = h1bf + ((size_t)(b*PP + pt*64 + lr))*64 + kb8;
    const unsigned short* wb0 = g2wBf + (size_t)(c0 + w*16 + lr)*64 + kb8;
    const unsigned short* wb1 = wb0 + 64*64;
    #pragma unroll
    for (int ks=0; ks<2; ++ks){
      short8 ga0 = *(const short8*)(wb0 + ks*32);
      short8 ga1 = *(const short8*)(wb1 + ks*32);
      #pragma unroll
      for (int nf=0; nf<4; ++nf){
        short8 bv = *(const short8*)(hbase + (size_t)nf*16*64 + ks*32);
        gac[0][nf] = __builtin_amdgcn_mfma_f32_16x16x32_bf16(ga0, bv, gac[0][nf], 0,0,0);
        gac[1][nf] = __builtin_amdgcn_mfma_f32_16x16x32_bf16(ga1, bv, gac[1][nf], 0,0,0);
      }
    }
  }

  // ---- skip-phase A-frag prefetch (chunk 0): [buf][m*2+ks] ----
  const unsigned short* wbS0 = WsumBf + (size_t)(c0 + w*16 + lr)*CCH + kb8;
  const unsigned short* wbS1 = wbS0 + 64*CCH;
  short8 af[2][4];
  af[0][0] = *(const short8*)(wbS0);
  af[0][1] = *(const short8*)(wbS0 + 32);
  af[0][2] = *(const short8*)(wbS1);
  af[0][3] = *(const short8*)(wbS1 + 32);

  f32x4 accS[2][4] = {};
  __syncthreads();   // chunk 0 staged

  // ---- main K loop: 6 chunks of 64, double-buffered ----
  #pragma unroll
  for (int c = 0; c < 6; ++c) {
    int cb = c & 1, nb2 = cb ^ 1;
    if (c < 5) {
      int ga = g0, gb2 = g0 + 64;
      int pa = ga>>3, pb = gb2>>3;
      int ka = ((ga&7) ^ (pa&7))*8, kb = ((gb2&7) ^ (pb&7))*8;
      gload_lds16(xrow0 + (size_t)pa*CCH + (c+1)*64 + ka, &xt[nb2][(size_t)(w*128)*8]);
      gload_lds16(xrow0 + (size_t)pb*CCH + (c+1)*64 + kb, &xt[nb2][(size_t)(w*128+64)*8]);
      af[nb2][0] = *(const short8*)(wbS0 + (c+1)*64);
      af[nb2][1] = *(const short8*)(wbS0 + (c+1)*64 + 32);
      af[nb2][2] = *(const short8*)(wbS1 + (c+1)*64);
      af[nb2][3] = *(const short8*)(wbS1 + (c+1)*64 + 32);
    }
    #pragma unroll
    for (int ks=0; ks<2; ++ks){
      int kg = ks*4 + kq;
      #pragma unroll
      for (int nf=0; nf<4; ++nf){
        int pr = nf*16 + lr;
        short8 bv = *(const short8*)&xt[cb][(size_t)(pr*8 + (kg ^ (pr & 7)))*8];
        accS[0][nf] = __builtin_amdgcn_mfma_f32_16x16x32_bf16(af[cb][ks],   bv, accS[0][nf], 0,0,0);
        accS[1][nf] = __builtin_amdgcn_mfma_f32_16x16x32_bf16(af[cb][2+ks], bv, accS[1][nf], 0,0,0);
      }
    }
    __syncthreads();
  }

  // ---- phase C: Wout contraction via MFMA, K=32, B from global hscat (L2-hot) ----
  f32x4 yac[2][4] = {};
  {
    const unsigned short* hb2 = hscat + ((size_t)(b*PP + pt*64 + lr))*32 + kb8;
    const unsigned short* wo0 = WocatBf + (size_t)(c0 + w*16 + lr)*32 + kb8;
    short8 wa0 = *(const short8*)wo0;
    short8 wa1 = *(const short8*)(wo0 + 64*32);
    #pragma unroll
    for (int nf=0; nf<4; ++nf){
      short8 hv = *(const short8*)(hb2 + (size_t)nf*16*32);
      yac[0][nf] = __builtin_amdgcn_mfma_f32_16x16x32_bf16(wa0, hv, yac[0][nf], 0,0,0);
      yac[1][nf] = __builtin_amdgcn_mfma_f32_16x16x32_bf16(wa1, hv, yac[1][nf], 0,0,0);
    }
  }

  // ---- epilogue ----
  int crow = w*16 + kq*4;
  #pragma unroll
  for (int m=0;m<2;++m){
    #pragma unroll
    for (int r=0;r<4;++r){
      int c = c0 + m*64 + crow + r;
      float cbv = 2.f*(boR[c]+bsR[c]+boC[c]+bsC[c]);
      float gbv = g2b[c];
      #pragma unroll
      for (int nf=0;nf<4;++nf){
        size_t addr = ((size_t)(b*CCH + c))*PP + pt*64 + nf*16 + lr;
        float xv = x[addr];
        float y = 0.25f*(yac[m][nf][r] + 2.f*accS[m][nf][r] + cbv);
        float gt = sigmoidf_(gac[m][nf][r] + gbv);
        outp[addr] = gt*y + (1.f-gt)*xv;
      }
    }
  }
}

extern "C" void kernel_launch(void* const* d_in, const int* in_sizes, int n_in,
                              void* d_out, int out_size, void* d_ws, size_t ws_size,
                              hipStream_t stream)
{
  const float* x    = (const float*)d_in[0];
  const float* rAl  = (const float*)d_in[1];
  const float* rU   = (const float*)d_in[2];
  const float* rV   = (const float*)d_in[3];
  const float* rWin = (const float*)d_in[4];
  const float* rbin = (const float*)d_in[5];
  const float* rWg  = (const float*)d_in[6];
  const float* rbg  = (const float*)d_in[7];
  const float* rWo  = (const float*)d_in[8];
  const float* rbo  = (const float*)d_in[9];
  const float* rWs  = (const float*)d_in[10];
  const float* rbs  = (const float*)d_in[11];
  const float* cAl  = (const float*)d_in[12];
  const float* cU   = (const float*)d_in[13];
  const float* cV   = (const float*)d_in[14];
  const float* cWin = (const float*)d_in[15];
  const float* cbin = (const float*)d_in[16];
  const float* cWg  = (const float*)d_in[17];
  const float* cbg  = (const float*)d_in[18];
  const float* cWo  = (const float*)d_in[19];
  const float* cbo  = (const float*)d_in[20];
  const float* cWs  = (const float*)d_in[21];
  const float* cbs  = (const float*)d_in[22];
  const float* g1w  = (const float*)d_in[23];
  const float* g1b  = (const float*)d_in[24];
  const float* g2w  = (const float*)d_in[25];
  const float* g2b  = (const float*)d_in[26];
  const float* nw   = (const float*)d_in[27];
  const float* nb   = (const float*)d_in[28];

  float* ws   = (float*)d_ws;
  float* ugr  = ws;                    // 1048576 (B,P,16) fp32
  float* ugc  = ugr + 1048576;         // 1048576
  float* Arow = ugc + 1048576;         // 256
  float* Acol = Arow + 256;            // 256
  float* t1   = Acol + 256;            // 64
  float* t2   = t1 + 64;               // 64
  unsigned short* xbf     = (unsigned short*)(t2 + 64);   // 16*4096*384 = 25165824
  unsigned short* h1bf    = xbf + (size_t)25165824;       // 16*4096*64  = 4194304
  unsigned short* hscat   = h1bf + (size_t)4194304;       // 16*4096*32  = 2097152
  unsigned short* WsumBf  = hscat + (size_t)2097152;      // 147456
  unsigned short* WcatBf  = WsumBf + 147456;              // 49152
  unsigned short* g2wBf   = WcatBf + 49152;               // 24576
  unsigned short* WocatBf = g2wBf + 24576;                // 12288
  float* outp = (float*)d_out;

  k_prep<<<913, 256, 0, stream>>>(rAl,rU,rV,cAl,cU,cV,rWs,cWs,
                                  rWin,rWg,cWin,cWg,g1w,nw,nb,g2w,rWo,cWo,
                                  Arow,Acol,WsumBf,WcatBf,g2wBf,WocatBf,t1,t2);
  k_xf<<<1024, 256, 0, stream>>>(x, WcatBf, rbin, rbg, cbin, cbg,
                                 t1, t2, g1b, xbf, ugr, ugc, h1bf);
  k_scan<<<128, 256, 0, stream>>>(ugr, ugc, Arow, Acol, hscat);
  k_fused<<<3072, 256, 0, stream>>>(x, xbf, WsumBf, h1bf, g2wBf,
                                    hscat, WocatBf, g2b,
                                    rbo, rbs, cbo, cbs, outp);
}